// Round 12
// baseline (4155.665 us; speedup 1.0000x reference)
//
#include <hip/hip_runtime.h>
#include <hip/hip_bf16.h>
#include <math.h>

#define SLEN 256
#define BSZ  16
#define NH   8
#define HD   64
#define HID  512
#define FFD  2048
#define MROWS (SLEN*BSZ)   // 4096

typedef __attribute__((ext_vector_type(8))) short short8v;
typedef __attribute__((ext_vector_type(4))) short short4v;
typedef __attribute__((ext_vector_type(4))) float float4v;
typedef unsigned short ushort_t;
typedef unsigned int uint_t;

// lgkmcnt-only barrier: LDS visibility without draining vmcnt.
#define SYNC_LDS() do { \
  asm volatile("s_waitcnt lgkmcnt(0)" ::: "memory"); \
  __builtin_amdgcn_s_barrier(); \
} while (0)

// ---- all-VALU wave-64 reductions: 4 DPP xor levels + row_bcast15/31 + readlane ----
template<int C> __device__ __forceinline__ float dppf(float x){
  return __int_as_float(__builtin_amdgcn_update_dpp(__float_as_int(x), __float_as_int(x), C, 0xF, 0xF, false));
}

__device__ __forceinline__ float rsum64(float v){
  v += dppf<0xB1>(v);   // xor 1
  v += dppf<0x4E>(v);   // xor 2
  v += dppf<0x141>(v);  // row_half_mirror (xor 4 level)
  v += dppf<0x140>(v);  // row_mirror      (xor 8 level)
  v += __int_as_float(__builtin_amdgcn_update_dpp(0, __float_as_int(v), 0x142, 0xa, 0xF, false)); // bcast15
  v += __int_as_float(__builtin_amdgcn_update_dpp(0, __float_as_int(v), 0x143, 0xc, 0xF, false)); // bcast31
  return __int_as_float(__builtin_amdgcn_readlane(__float_as_int(v), 63));
}

__device__ __forceinline__ void split_bf16(float f, ushort_t& h, ushort_t& l){
  unsigned u = __float_as_uint(f);
  unsigned r = u + (0x7fffu + ((u >> 16) & 1u));
  h = (ushort_t)(r >> 16);
  float hf = __uint_as_float(((unsigned)h) << 16);
  float lo = f - hf;
  unsigned u2 = __float_as_uint(lo);
  unsigned r2 = u2 + (0x7fffu + ((u2 >> 16) & 1u));
  l = (ushort_t)(r2 >> 16);
}

__device__ __forceinline__ uint_t pack_bf16(float f){
  ushort_t h, l; split_bf16(f, h, l);
  return ((uint_t)h << 16) | (uint_t)l;
}

// ---------------- MFMA GEMM, bf16x3 split, BN=128 tile (for N=2048) ----------------
template<int N, int K, int AMODE, bool BIAS, bool RESID, bool RELU, bool PACKOUT>
__global__ __launch_bounds__(512) void gemm128(
    const void* __restrict__ Ax, const float* __restrict__ B,
    const float* __restrict__ bias, const float* __restrict__ resid,
    void* __restrict__ Cx)
{
  __shared__ ushort_t Ah[128][40];
  __shared__ ushort_t Al[128][40];
  __shared__ ushort_t Bh[128][40];   // [col][k]
  __shared__ ushort_t Bl[128][40];

  const int tid = threadIdx.x;
  const int wv = tid >> 6, lane = tid & 63;
  const int wm = wv >> 2, wn = wv & 3;
  const int l15 = lane & 15, l16 = lane >> 4;
  const int row0 = blockIdx.y * 128, col0 = blockIdx.x * 128;

  const int sar = tid >> 2, sak = (tid & 3) * 8;
  const int sbc = tid & 127, sbk = (tid >> 7) * 8;

  float4v acc[4][2];
#pragma unroll
  for (int i = 0; i < 4; ++i)
#pragma unroll
    for (int n = 0; n < 2; ++n) acc[i][n] = (float4v)(0.f);

  for (int k0 = 0; k0 < K; k0 += 32) {
    {
      short8v vh, vl;
      if (AMODE == 0) {
        const float* ap = (const float*)Ax + (size_t)(row0 + sar) * K + k0 + sak;
        float4 a0 = *reinterpret_cast<const float4*>(ap);
        float4 a1 = *reinterpret_cast<const float4*>(ap + 4);
        float av[8] = {a0.x, a0.y, a0.z, a0.w, a1.x, a1.y, a1.z, a1.w};
#pragma unroll
        for (int j = 0; j < 8; ++j) {
          ushort_t h, l; split_bf16(av[j], h, l);
          vh[j] = (short)h; vl[j] = (short)l;
        }
      } else {
        const uint_t* ap = (const uint_t*)Ax + (size_t)(row0 + sar) * K + k0 + sak;
        uint4 a0 = *reinterpret_cast<const uint4*>(ap);
        uint4 a1 = *reinterpret_cast<const uint4*>(ap + 4);
        uint_t av[8] = {a0.x, a0.y, a0.z, a0.w, a1.x, a1.y, a1.z, a1.w};
#pragma unroll
        for (int j = 0; j < 8; ++j) {
          vh[j] = (short)(av[j] >> 16);
          vl[j] = (short)(av[j] & 0xffffu);
        }
      }
      *reinterpret_cast<short8v*>(&Ah[sar][sak]) = vh;
      *reinterpret_cast<short8v*>(&Al[sar][sak]) = vl;
    }
    {
      float bv[8];
#pragma unroll
      for (int j = 0; j < 8; ++j)
        bv[j] = B[(size_t)(k0 + sbk + j) * N + col0 + sbc];
      short8v vh, vl;
#pragma unroll
      for (int j = 0; j < 8; ++j) {
        ushort_t h, l; split_bf16(bv[j], h, l);
        vh[j] = (short)h; vl[j] = (short)l;
      }
      *reinterpret_cast<short8v*>(&Bh[sbc][sbk]) = vh;
      *reinterpret_cast<short8v*>(&Bl[sbc][sbk]) = vl;
    }
    __syncthreads();

    short8v ah[4], al[4], bh[2], bl[2];
#pragma unroll
    for (int i = 0; i < 4; ++i) {
      const int r = wm * 64 + i * 16 + l15;
      ah[i] = *reinterpret_cast<const short8v*>(&Ah[r][l16 * 8]);
      al[i] = *reinterpret_cast<const short8v*>(&Al[r][l16 * 8]);
    }
#pragma unroll
    for (int n = 0; n < 2; ++n) {
      const int c = wn * 32 + n * 16 + l15;
      bh[n] = *reinterpret_cast<const short8v*>(&Bh[c][l16 * 8]);
      bl[n] = *reinterpret_cast<const short8v*>(&Bl[c][l16 * 8]);
    }
#pragma unroll
    for (int i = 0; i < 4; ++i)
#pragma unroll
      for (int n = 0; n < 2; ++n) {
        acc[i][n] = __builtin_amdgcn_mfma_f32_16x16x32_bf16(ah[i], bh[n], acc[i][n], 0, 0, 0);
        acc[i][n] = __builtin_amdgcn_mfma_f32_16x16x32_bf16(ah[i], bl[n], acc[i][n], 0, 0, 0);
        acc[i][n] = __builtin_amdgcn_mfma_f32_16x16x32_bf16(al[i], bh[n], acc[i][n], 0, 0, 0);
      }
    __syncthreads();
  }

#pragma unroll
  for (int i = 0; i < 4; ++i) {
#pragma unroll
    for (int n = 0; n < 2; ++n) {
      const int col = col0 + wn * 32 + n * 16 + l15;
      float bs = BIAS ? bias[col] : 0.f;
#pragma unroll
      for (int r = 0; r < 4; ++r) {
        const int row = row0 + wm * 64 + i * 16 + l16 * 4 + r;
        float v = acc[i][n][r] + bs;
        if (RESID) v += resid[(size_t)row * N + col];
        if (RELU)  v = fmaxf(v, 0.f);
        if (PACKOUT) ((uint_t*)Cx)[(size_t)row * N + col] = pack_bf16(v);
        else         ((float*)Cx)[(size_t)row * N + col] = v;
      }
    }
  }
}

// ---------------- MFMA GEMM, bf16x3 split, BN=64 tile (for N=512) ----------------
template<int N, int K, int AMODE, bool BIAS, bool RESID, bool RELU, bool PACKOUT>
__global__ __launch_bounds__(512) void gemm64(
    const void* __restrict__ Ax, const float* __restrict__ B,
    const float* __restrict__ bias, const float* __restrict__ resid,
    void* __restrict__ Cx)
{
  __shared__ ushort_t Ah[128][40];
  __shared__ ushort_t Al[128][40];
  __shared__ ushort_t Bh[64][40];   // [col][k]
  __shared__ ushort_t Bl[64][40];

  const int tid = threadIdx.x;
  const int wv = tid >> 6, lane = tid & 63;
  const int wm = wv >> 1;          // 0..3 : 32-row band
  const int wn = wv & 1;           // 0..1 : 32-col half
  const int l15 = lane & 15, l16 = lane >> 4;
  const int row0 = blockIdx.y * 128, col0 = blockIdx.x * 64;

  const int sar = tid >> 2, sak = (tid & 3) * 8;    // A: 128r x 32k, 8/thread
  const int sbc = tid & 63,  sbk = (tid >> 6) * 4;  // B: 64c x 32k, 4/thread

  float4v acc[2][2];
#pragma unroll
  for (int i = 0; i < 2; ++i)
#pragma unroll
    for (int n = 0; n < 2; ++n) acc[i][n] = (float4v)(0.f);

  for (int k0 = 0; k0 < K; k0 += 32) {
    {
      short8v vh, vl;
      if (AMODE == 0) {
        const float* ap = (const float*)Ax + (size_t)(row0 + sar) * K + k0 + sak;
        float4 a0 = *reinterpret_cast<const float4*>(ap);
        float4 a1 = *reinterpret_cast<const float4*>(ap + 4);
        float av[8] = {a0.x, a0.y, a0.z, a0.w, a1.x, a1.y, a1.z, a1.w};
#pragma unroll
        for (int j = 0; j < 8; ++j) {
          ushort_t h, l; split_bf16(av[j], h, l);
          vh[j] = (short)h; vl[j] = (short)l;
        }
      } else {
        const uint_t* ap = (const uint_t*)Ax + (size_t)(row0 + sar) * K + k0 + sak;
        uint4 a0 = *reinterpret_cast<const uint4*>(ap);
        uint4 a1 = *reinterpret_cast<const uint4*>(ap + 4);
        uint_t av[8] = {a0.x, a0.y, a0.z, a0.w, a1.x, a1.y, a1.z, a1.w};
#pragma unroll
        for (int j = 0; j < 8; ++j) {
          vh[j] = (short)(av[j] >> 16);
          vl[j] = (short)(av[j] & 0xffffu);
        }
      }
      *reinterpret_cast<short8v*>(&Ah[sar][sak]) = vh;
      *reinterpret_cast<short8v*>(&Al[sar][sak]) = vl;
    }
    {
      float bv[4];
#pragma unroll
      for (int j = 0; j < 4; ++j)
        bv[j] = B[(size_t)(k0 + sbk + j) * N + col0 + sbc];
      short4v vh, vl;
#pragma unroll
      for (int j = 0; j < 4; ++j) {
        ushort_t h, l; split_bf16(bv[j], h, l);
        vh[j] = (short)h; vl[j] = (short)l;
      }
      *reinterpret_cast<short4v*>(&Bh[sbc][sbk]) = vh;
      *reinterpret_cast<short4v*>(&Bl[sbc][sbk]) = vl;
    }
    __syncthreads();

    short8v ah[2], al[2], bh[2], bl[2];
#pragma unroll
    for (int i = 0; i < 2; ++i) {
      const int r = wm * 32 + i * 16 + l15;
      ah[i] = *reinterpret_cast<const short8v*>(&Ah[r][l16 * 8]);
      al[i] = *reinterpret_cast<const short8v*>(&Al[r][l16 * 8]);
    }
#pragma unroll
    for (int n = 0; n < 2; ++n) {
      const int c = wn * 32 + n * 16 + l15;
      bh[n] = *reinterpret_cast<const short8v*>(&Bh[c][l16 * 8]);
      bl[n] = *reinterpret_cast<const short8v*>(&Bl[c][l16 * 8]);
    }
#pragma unroll
    for (int i = 0; i < 2; ++i)
#pragma unroll
      for (int n = 0; n < 2; ++n) {
        acc[i][n] = __builtin_amdgcn_mfma_f32_16x16x32_bf16(ah[i], bh[n], acc[i][n], 0, 0, 0);
        acc[i][n] = __builtin_amdgcn_mfma_f32_16x16x32_bf16(ah[i], bl[n], acc[i][n], 0, 0, 0);
        acc[i][n] = __builtin_amdgcn_mfma_f32_16x16x32_bf16(al[i], bh[n], acc[i][n], 0, 0, 0);
      }
    __syncthreads();
  }

#pragma unroll
  for (int i = 0; i < 2; ++i) {
#pragma unroll
    for (int n = 0; n < 2; ++n) {
      const int col = col0 + wn * 32 + n * 16 + l15;
      float bs = BIAS ? bias[col] : 0.f;
#pragma unroll
      for (int r = 0; r < 4; ++r) {
        const int row = row0 + wm * 32 + i * 16 + l16 * 4 + r;
        float v = acc[i][n][r] + bs;
        if (RESID) v += resid[(size_t)row * N + col];
        if (RELU)  v = fmaxf(v, 0.f);
        if (PACKOUT) ((uint_t*)Cx)[(size_t)row * N + col] = pack_bf16(v);
        else         ((float*)Cx)[(size_t)row * N + col] = v;
      }
    }
  }
}

// ---------------- layernorm over HID=512, packed bf16-pair output ----------------
__global__ __launch_bounds__(64) void layernorm_k(
    const float* __restrict__ in, const float* __restrict__ g,
    const float* __restrict__ b, uint_t* __restrict__ out)
{
  const int row = blockIdx.x, lane = threadIdx.x;
  const float* p = in + (size_t)row * HID + lane * 8;
  float4 v0 = *reinterpret_cast<const float4*>(p);
  float4 v1 = *reinterpret_cast<const float4*>(p + 4);
  float s = v0.x + v0.y + v0.z + v0.w + v1.x + v1.y + v1.z + v1.w;
  s = rsum64(s);
  const float mean = s * (1.0f / HID);
  float x[8] = {v0.x, v0.y, v0.z, v0.w, v1.x, v1.y, v1.z, v1.w};
  float sq = 0.f;
#pragma unroll
  for (int j = 0; j < 8; ++j) { float d = x[j] - mean; sq += d * d; }
  sq = rsum64(sq);
  const float rstd = rsqrtf(sq * (1.0f / HID) + 1e-5f);
  float4 g0 = *reinterpret_cast<const float4*>(&g[lane * 8]);
  float4 g1 = *reinterpret_cast<const float4*>(&g[lane * 8 + 4]);
  float4 b0 = *reinterpret_cast<const float4*>(&b[lane * 8]);
  float4 b1 = *reinterpret_cast<const float4*>(&b[lane * 8 + 4]);
  float gg[8] = {g0.x, g0.y, g0.z, g0.w, g1.x, g1.y, g1.z, g1.w};
  float bb[8] = {b0.x, b0.y, b0.z, b0.w, b1.x, b1.y, b1.z, b1.w};
  uint_t o[8];
#pragma unroll
  for (int j = 0; j < 8; ++j) o[j] = pack_bf16((x[j] - mean) * rstd * gg[j] + bb[j]);
  uint4 o0 = make_uint4(o[0], o[1], o[2], o[3]);
  uint4 o1 = make_uint4(o[4], o[5], o[6], o[7]);
  uint_t* q = out + (size_t)row * HID + lane * 8;
  *reinterpret_cast<uint4*>(q) = o0;
  *reinterpret_cast<uint4*>(q + 4) = o1;
}

// ---------------- fast-weight recurrence: 4 waves per chain, staggered LDS reads ----------------
// R9 srec4m (best, 313us: merged interval [B(t-1); A(t)] + 1 barrier/step, no
// max-sub softmax, independent wave3 reductions, rcp sigmoid), with each W-wave's
// uniform-broadcast LDS read sequence ROTATED by wv*2 quads. After each barrier
// all 3 W-waves previously issued identical 16-quad bursts at the same instant,
// serializing ~3x on the CU's single LDS pipe right on the critical path; the
// rotation de-correlates the bursts. Same addresses, same W-pairing — only
// accumulation order within independent accumulators changes (rounding noise).
__global__ __launch_bounds__(256) void srec4g(
    const float* __restrict__ h,
    const float* __restrict__ Wy0, const float* __restrict__ Wq0,
    const float* __restrict__ Wk0, const float* __restrict__ wb0,
    uint_t* __restrict__ ys)
{
  const int bh = blockIdx.x;
  const int bb = bh >> 3, hh = bh & 7;
  const int tid = threadIdx.x;
  const int wv = tid >> 6, lane = tid & 63;

  __shared__ float xs[2][64];
  __shared__ float q_s[2][64];
  __shared__ float k_s[2][64];
  __shared__ float4 betas4[2];

  float W[64];
  float wbr[4] = {0.f, 0.f, 0.f, 0.f};
  float xrA = 0.f, xrB = 0.f;   // raw-x prefetch registers (alternating)
  float xnreg = 0.f;            // softmax(x(t+1)), carried interval -> interval

  const float* xp = h + (size_t)bb * HID + hh * 64 + lane;
  uint_t* yp = ys + (size_t)bb * HID + hh * 64 + lane;

  if (wv < 3) {
    const float* base = (wv == 0 ? Wy0 : (wv == 1 ? Wq0 : Wk0)) + (size_t)(hh * 64 + lane) * 64;
#pragma unroll
    for (int j = 0; j < 16; ++j) {
      float4 a = reinterpret_cast<const float4*>(base)[j];
      W[4*j] = a.x; W[4*j+1] = a.y; W[4*j+2] = a.z; W[4*j+3] = a.w;
    }
  } else {
    float4 w = *reinterpret_cast<const float4*>(&wb0[(size_t)(hh * 64 + lane) * 4]);
    wbr[0] = w.x; wbr[1] = w.y; wbr[2] = w.z; wbr[3] = w.w;
    float xr0 = xp[0];
    xrA = xp[(size_t)BSZ * HID];       // raw x(1)
    // softmax(x(0)) -> xs[0]   (no max-sub: shift-invariant)
    float e = __expf(xr0);
    float sm = rsum64(e);
    float x0 = e * __builtin_amdgcn_rcpf(sm);
    xs[0][lane] = x0;
    // betas for step 0
    float s0 = rsum64(wbr[0] * x0);
    float s1 = rsum64(wbr[1] * x0);
    float s2 = rsum64(wbr[2] * x0);
    float s3 = rsum64(wbr[3] * x0);
    if (lane == 0)
      betas4[0] = make_float4(__builtin_amdgcn_rcpf(1.f + __expf(-s0)),
                              __builtin_amdgcn_rcpf(1.f + __expf(-s1)),
                              __builtin_amdgcn_rcpf(1.f + __expf(-s2)),
                              __builtin_amdgcn_rcpf(1.f + __expf(-s3)));
  }
  SYNC_LDS();

  // ---- A-part of step T (phase parity P = T&1): matvec + softmax publish ----
  auto Apart = [&](int P, float& XCUR, float& XNEXT, int T) {
    if (wv == 3) {
      if (T + 2 < SLEN) XNEXT = xp[(size_t)(T + 2) * BSZ * HID];  // issue; used 2 intervals later
      // softmax of raw x(T+1) -> xs[1-P]   (no max-sub)
      float e = __expf(XCUR);
      float sm = rsum64(e);
      float xn_ = e * __builtin_amdgcn_rcpf(sm);
      xs[1 - P][lane] = xn_;
      xnreg = xn_;
    } else {
      const float4* xv = reinterpret_cast<const float4*>(xs[P]);
      float a0=0.f,a1=0.f,a2=0.f,a3=0.f,a4=0.f,a5=0.f,a6=0.f,a7=0.f;
#pragma unroll
      for (int jj = 0; jj < 8; ++jj) {
        const int j = (jj + wv * 2) & 7;           // staggered start per wave
        float4 x1 = xv[2*j], x2 = xv[2*j+1];
        a0 = fmaf(W[8*j+0], x1.x, a0);
        a1 = fmaf(W[8*j+1], x1.y, a1);
        a2 = fmaf(W[8*j+2], x1.z, a2);
        a3 = fmaf(W[8*j+3], x1.w, a3);
        a4 = fmaf(W[8*j+4], x2.x, a4);
        a5 = fmaf(W[8*j+5], x2.y, a5);
        a6 = fmaf(W[8*j+6], x2.z, a6);
        a7 = fmaf(W[8*j+7], x2.w, a7);
      }
      float acc = ((a0 + a1) + (a2 + a3)) + ((a4 + a5) + (a6 + a7));
      if (wv == 0) {
        yp[(size_t)T * BSZ * HID] = pack_bf16(acc);   // fire-and-forget packed store
      } else {
        float e = __expf(acc);             // no max-sub
        float sm = rsum64(e);
        float v = e * __builtin_amdgcn_rcpf(sm);
        float* dst = (wv == 1) ? q_s[P] : k_s[P];
        dst[lane] = v;
      }
    }
  };

  // ---- B-part of step T (P = T&1): W/wb update + betas for step T+1 ----
  auto Bpart = [&](int P) {
    float4 bb4 = betas4[P];
    if (wv < 3) {
      const float4* qv = reinterpret_cast<const float4*>(q_s[P]);
      const float4* kv = reinterpret_cast<const float4*>(k_s[P]);
      float4 karr[16];
      float a0=0.f,a1=0.f,a2=0.f,a3=0.f,a4=0.f,a5=0.f,a6=0.f,a7=0.f;
#pragma unroll
      for (int jj = 0; jj < 8; ++jj) {
        const int j = (jj + wv * 2) & 7;           // staggered start per wave
        float4 q1 = qv[2*j], k1 = kv[2*j];
        float4 q2 = qv[2*j+1], k2 = kv[2*j+1];
        karr[2*j] = k1; karr[2*j+1] = k2;
        a0 = fmaf(W[8*j+0], q1.x - k1.x, a0);
        a1 = fmaf(W[8*j+1], q1.y - k1.y, a1);
        a2 = fmaf(W[8*j+2], q1.z - k1.z, a2);
        a3 = fmaf(W[8*j+3], q1.w - k1.w, a3);
        a4 = fmaf(W[8*j+4], q2.x - k2.x, a4);
        a5 = fmaf(W[8*j+5], q2.y - k2.y, a5);
        a6 = fmaf(W[8*j+6], q2.z - k2.z, a6);
        a7 = fmaf(W[8*j+7], q2.w - k2.w, a7);
      }
      float dd = ((a0 + a1) + (a2 + a3)) + ((a4 + a5) + (a6 + a7));
      float beta = (wv == 0) ? bb4.x : (wv == 1 ? bb4.y : bb4.z);
      float c = beta * dd;
#pragma unroll
      for (int j = 0; j < 16; ++j) {
        float4 k4 = karr[j];
        W[4*j]   = fmaf(c, k4.x, W[4*j]);
        W[4*j+1] = fmaf(c, k4.y, W[4*j+1]);
        W[4*j+2] = fmaf(c, k4.z, W[4*j+2]);
        W[4*j+3] = fmaf(c, k4.w, W[4*j+3]);
      }
    } else {
      // wb update + next-step betas via 9 INDEPENDENT reductions:
      // s_i(next) = (wbr_i + bk*d_i) . xn = rsum(wbr_i*xn) + d_i * rsum(bk*xn)
      float ql = q_s[P][lane], kl = k_s[P][lane];
      float dl = ql - kl;
      float bk = bb4.w * kl;
      float u0 = rsum64(wbr[0] * xnreg);
      float u1 = rsum64(wbr[1] * xnreg);
      float u2 = rsum64(wbr[2] * xnreg);
      float u3 = rsum64(wbr[3] * xnreg);
      float d0 = rsum64(wbr[0] * dl);
      float d1 = rsum64(wbr[1] * dl);
      float d2 = rsum64(wbr[2] * dl);
      float d3 = rsum64(wbr[3] * dl);
      float g  = rsum64(bk * xnreg);
      wbr[0] = fmaf(bk, d0, wbr[0]);
      wbr[1] = fmaf(bk, d1, wbr[1]);
      wbr[2] = fmaf(bk, d2, wbr[2]);
      wbr[3] = fmaf(bk, d3, wbr[3]);
      float s0 = fmaf(d0, g, u0);
      float s1 = fmaf(d1, g, u1);
      float s2 = fmaf(d2, g, u2);
      float s3 = fmaf(d3, g, u3);
      if (lane == 0)
        betas4[1 - P] = make_float4(__builtin_amdgcn_rcpf(1.f + __expf(-s0)),
                                    __builtin_amdgcn_rcpf(1.f + __expf(-s1)),
                                    __builtin_amdgcn_rcpf(1.f + __expf(-s2)),
                                    __builtin_amdgcn_rcpf(1.f + __expf(-s3)));
    }
  };

  // interval 0: A(0) only
  Apart(0, xrA, xrB, 0);
  SYNC_LDS();
  // intervals 1..254 (pairs): [B(t-1); A(t)] + one barrier each
  for (int t = 1; t < SLEN - 1; t += 2) {
    Bpart(0);  Apart(1, xrB, xrA, t);      SYNC_LDS();
    Bpart(1);  Apart(0, xrA, xrB, t + 1);  SYNC_LDS();
  }
  // final interval: B(254); A(255). Dead update B(255) skipped.
  Bpart(0);  Apart(1, xrB, xrA, SLEN - 1);
}

extern "C" void kernel_launch(void* const* d_in, const int* in_sizes, int n_in,
                              void* d_out, int out_size, void* d_ws, size_t ws_size,
                              hipStream_t stream)
{
  const float* x     = (const float*)d_in[0];
  const float* in_w  = (const float*)d_in[1];
  const float* in_b  = (const float*)d_in[2];
  const float* Wy    = (const float*)d_in[3];
  const float* Wq    = (const float*)d_in[4];
  const float* Wk    = (const float*)d_in[5];
  const float* wb    = (const float*)d_in[6];
  const float* Wout  = (const float*)d_in[7];
  const float* ln_g  = (const float*)d_in[8];
  const float* ln_b  = (const float*)d_in[9];
  const float* ff_w1 = (const float*)d_in[10];
  const float* ff_b1 = (const float*)d_in[11];
  const float* ff_w2 = (const float*)d_in[12];
  const float* ff_b2 = (const float*)d_in[13];
  float* out = (float*)d_out;

  char* ws = (char*)d_ws;
  uint_t* ys   = (uint_t*)ws;                  // 8MB  packed bf16-pair
  uint_t* ffb  = (uint_t*)(ws + (8u  << 20));  // 32MB packed
  uint_t* ybuf = (uint_t*)(ws + (40u << 20));  // 8MB  packed

  // ---- in-projection: A fp32 x, B fp32 in_w, C fp32 out. 256 blocks (full GPU). ----
  gemm64<HID, 512, 0, true, false, false, false><<<dim3(HID/64, MROWS/128), 512, 0, stream>>>(
      x, in_w, in_b, nullptr, out);

  for (int l = 0; l < 2; ++l) {
    srec4g<<<128, 256, 0, stream>>>(out,
                                    Wy + (size_t)l * NH * HD * HD,
                                    Wq + (size_t)l * NH * HD * HD,
                                    Wk + (size_t)l * NH * HD * HD,
                                    wb + (size_t)l * NH * HD * 4,
                                    ys);
    // Wout: A packed ys, B fp32, resid fp32 out, C fp32 out. 256 blocks.
    gemm64<HID, HID, 1, false, true, false, false><<<dim3(HID/64, MROWS/128), 512, 0, stream>>>(
        ys, Wout + (size_t)l * HID * HID, nullptr, out, out);
    layernorm_k<<<MROWS, 64, 0, stream>>>(out, ln_g + (size_t)l * HID, ln_b + (size_t)l * HID, ybuf);
    // FF1: A packed ybuf, B fp32, relu, C packed ffb. 512 blocks (2/CU).
    gemm128<FFD, HID, 1, true, false, true, true><<<dim3(FFD/128, MROWS/128), 512, 0, stream>>>(
        ybuf, ff_w1 + (size_t)l * HID * FFD, ff_b1 + (size_t)l * FFD, nullptr, ffb);
    // FF2: A packed ffb, B fp32, resid fp32 out, C fp32 out. 256 blocks.
    gemm64<HID, FFD, 1, true, true, false, false><<<dim3(HID/64, MROWS/128), 512, 0, stream>>>(
        ffb, ff_w2 + (size_t)l * FFD * HID, ff_b2 + (size_t)l * HID, out, out);
  }
}

// Round 13
// 882.825 us; speedup vs baseline: 4.7072x; 4.7072x over previous
//
#include <hip/hip_runtime.h>
#include <hip/hip_bf16.h>
#include <math.h>

#define SLEN 256
#define BSZ  16
#define NH   8
#define HD   64
#define HID  512
#define FFD  2048
#define MROWS (SLEN*BSZ)   // 4096

typedef __attribute__((ext_vector_type(8))) short short8v;
typedef __attribute__((ext_vector_type(4))) short short4v;
typedef __attribute__((ext_vector_type(4))) float float4v;
typedef unsigned short ushort_t;
typedef unsigned int uint_t;

// lgkmcnt-only barrier: LDS visibility without draining vmcnt.
#define SYNC_LDS() do { \
  asm volatile("s_waitcnt lgkmcnt(0)" ::: "memory"); \
  __builtin_amdgcn_s_barrier(); \
} while (0)

// ---- all-VALU wave-64 reductions: 4 DPP xor levels + row_bcast15/31 + readlane ----
template<int C> __device__ __forceinline__ float dppf(float x){
  return __int_as_float(__builtin_amdgcn_update_dpp(__float_as_int(x), __float_as_int(x), C, 0xF, 0xF, false));
}

__device__ __forceinline__ float rsum64(float v){
  v += dppf<0xB1>(v);   // xor 1
  v += dppf<0x4E>(v);   // xor 2
  v += dppf<0x141>(v);  // row_half_mirror (xor 4 level)
  v += dppf<0x140>(v);  // row_mirror      (xor 8 level)
  v += __int_as_float(__builtin_amdgcn_update_dpp(0, __float_as_int(v), 0x142, 0xa, 0xF, false)); // bcast15
  v += __int_as_float(__builtin_amdgcn_update_dpp(0, __float_as_int(v), 0x143, 0xc, 0xF, false)); // bcast31
  return __int_as_float(__builtin_amdgcn_readlane(__float_as_int(v), 63));
}

__device__ __forceinline__ void split_bf16(float f, ushort_t& h, ushort_t& l){
  unsigned u = __float_as_uint(f);
  unsigned r = u + (0x7fffu + ((u >> 16) & 1u));
  h = (ushort_t)(r >> 16);
  float hf = __uint_as_float(((unsigned)h) << 16);
  float lo = f - hf;
  unsigned u2 = __float_as_uint(lo);
  unsigned r2 = u2 + (0x7fffu + ((u2 >> 16) & 1u));
  l = (ushort_t)(r2 >> 16);
}

__device__ __forceinline__ uint_t pack_bf16(float f){
  ushort_t h, l; split_bf16(f, h, l);
  return ((uint_t)h << 16) | (uint_t)l;
}

// ---------------- MFMA GEMM, bf16x3 split, BN=128 tile (for N=2048) ----------------
template<int N, int K, int AMODE, bool BIAS, bool RESID, bool RELU, bool PACKOUT>
__global__ __launch_bounds__(512) void gemm128(
    const void* __restrict__ Ax, const float* __restrict__ B,
    const float* __restrict__ bias, const float* __restrict__ resid,
    void* __restrict__ Cx)
{
  __shared__ ushort_t Ah[128][40];
  __shared__ ushort_t Al[128][40];
  __shared__ ushort_t Bh[128][40];   // [col][k]
  __shared__ ushort_t Bl[128][40];

  const int tid = threadIdx.x;
  const int wv = tid >> 6, lane = tid & 63;
  const int wm = wv >> 2, wn = wv & 3;
  const int l15 = lane & 15, l16 = lane >> 4;
  const int row0 = blockIdx.y * 128, col0 = blockIdx.x * 128;

  const int sar = tid >> 2, sak = (tid & 3) * 8;
  const int sbc = tid & 127, sbk = (tid >> 7) * 8;

  float4v acc[4][2];
#pragma unroll
  for (int i = 0; i < 4; ++i)
#pragma unroll
    for (int n = 0; n < 2; ++n) acc[i][n] = (float4v)(0.f);

  for (int k0 = 0; k0 < K; k0 += 32) {
    {
      short8v vh, vl;
      if (AMODE == 0) {
        const float* ap = (const float*)Ax + (size_t)(row0 + sar) * K + k0 + sak;
        float4 a0 = *reinterpret_cast<const float4*>(ap);
        float4 a1 = *reinterpret_cast<const float4*>(ap + 4);
        float av[8] = {a0.x, a0.y, a0.z, a0.w, a1.x, a1.y, a1.z, a1.w};
#pragma unroll
        for (int j = 0; j < 8; ++j) {
          ushort_t h, l; split_bf16(av[j], h, l);
          vh[j] = (short)h; vl[j] = (short)l;
        }
      } else {
        const uint_t* ap = (const uint_t*)Ax + (size_t)(row0 + sar) * K + k0 + sak;
        uint4 a0 = *reinterpret_cast<const uint4*>(ap);
        uint4 a1 = *reinterpret_cast<const uint4*>(ap + 4);
        uint_t av[8] = {a0.x, a0.y, a0.z, a0.w, a1.x, a1.y, a1.z, a1.w};
#pragma unroll
        for (int j = 0; j < 8; ++j) {
          vh[j] = (short)(av[j] >> 16);
          vl[j] = (short)(av[j] & 0xffffu);
        }
      }
      *reinterpret_cast<short8v*>(&Ah[sar][sak]) = vh;
      *reinterpret_cast<short8v*>(&Al[sar][sak]) = vl;
    }
    {
      float bv[8];
#pragma unroll
      for (int j = 0; j < 8; ++j)
        bv[j] = B[(size_t)(k0 + sbk + j) * N + col0 + sbc];
      short8v vh, vl;
#pragma unroll
      for (int j = 0; j < 8; ++j) {
        ushort_t h, l; split_bf16(bv[j], h, l);
        vh[j] = (short)h; vl[j] = (short)l;
      }
      *reinterpret_cast<short8v*>(&Bh[sbc][sbk]) = vh;
      *reinterpret_cast<short8v*>(&Bl[sbc][sbk]) = vl;
    }
    __syncthreads();

    short8v ah[4], al[4], bh[2], bl[2];
#pragma unroll
    for (int i = 0; i < 4; ++i) {
      const int r = wm * 64 + i * 16 + l15;
      ah[i] = *reinterpret_cast<const short8v*>(&Ah[r][l16 * 8]);
      al[i] = *reinterpret_cast<const short8v*>(&Al[r][l16 * 8]);
    }
#pragma unroll
    for (int n = 0; n < 2; ++n) {
      const int c = wn * 32 + n * 16 + l15;
      bh[n] = *reinterpret_cast<const short8v*>(&Bh[c][l16 * 8]);
      bl[n] = *reinterpret_cast<const short8v*>(&Bl[c][l16 * 8]);
    }
#pragma unroll
    for (int i = 0; i < 4; ++i)
#pragma unroll
      for (int n = 0; n < 2; ++n) {
        acc[i][n] = __builtin_amdgcn_mfma_f32_16x16x32_bf16(ah[i], bh[n], acc[i][n], 0, 0, 0);
        acc[i][n] = __builtin_amdgcn_mfma_f32_16x16x32_bf16(ah[i], bl[n], acc[i][n], 0, 0, 0);
        acc[i][n] = __builtin_amdgcn_mfma_f32_16x16x32_bf16(al[i], bh[n], acc[i][n], 0, 0, 0);
      }
    __syncthreads();
  }

#pragma unroll
  for (int i = 0; i < 4; ++i) {
#pragma unroll
    for (int n = 0; n < 2; ++n) {
      const int col = col0 + wn * 32 + n * 16 + l15;
      float bs = BIAS ? bias[col] : 0.f;
#pragma unroll
      for (int r = 0; r < 4; ++r) {
        const int row = row0 + wm * 64 + i * 16 + l16 * 4 + r;
        float v = acc[i][n][r] + bs;
        if (RESID) v += resid[(size_t)row * N + col];
        if (RELU)  v = fmaxf(v, 0.f);
        if (PACKOUT) ((uint_t*)Cx)[(size_t)row * N + col] = pack_bf16(v);
        else         ((float*)Cx)[(size_t)row * N + col] = v;
      }
    }
  }
}

// ---------------- MFMA GEMM, bf16x3 split, BN=64 tile (for N=512) ----------------
template<int N, int K, int AMODE, bool BIAS, bool RESID, bool RELU, bool PACKOUT>
__global__ __launch_bounds__(512) void gemm64(
    const void* __restrict__ Ax, const float* __restrict__ B,
    const float* __restrict__ bias, const float* __restrict__ resid,
    void* __restrict__ Cx)
{
  __shared__ ushort_t Ah[128][40];
  __shared__ ushort_t Al[128][40];
  __shared__ ushort_t Bh[64][40];   // [col][k]
  __shared__ ushort_t Bl[64][40];

  const int tid = threadIdx.x;
  const int wv = tid >> 6, lane = tid & 63;
  const int wm = wv >> 1;          // 0..3 : 32-row band
  const int wn = wv & 1;           // 0..1 : 32-col half
  const int l15 = lane & 15, l16 = lane >> 4;
  const int row0 = blockIdx.y * 128, col0 = blockIdx.x * 64;

  const int sar = tid >> 2, sak = (tid & 3) * 8;    // A: 128r x 32k, 8/thread
  const int sbc = tid & 63,  sbk = (tid >> 6) * 4;  // B: 64c x 32k, 4/thread

  float4v acc[2][2];
#pragma unroll
  for (int i = 0; i < 2; ++i)
#pragma unroll
    for (int n = 0; n < 2; ++n) acc[i][n] = (float4v)(0.f);

  for (int k0 = 0; k0 < K; k0 += 32) {
    {
      short8v vh, vl;
      if (AMODE == 0) {
        const float* ap = (const float*)Ax + (size_t)(row0 + sar) * K + k0 + sak;
        float4 a0 = *reinterpret_cast<const float4*>(ap);
        float4 a1 = *reinterpret_cast<const float4*>(ap + 4);
        float av[8] = {a0.x, a0.y, a0.z, a0.w, a1.x, a1.y, a1.z, a1.w};
#pragma unroll
        for (int j = 0; j < 8; ++j) {
          ushort_t h, l; split_bf16(av[j], h, l);
          vh[j] = (short)h; vl[j] = (short)l;
        }
      } else {
        const uint_t* ap = (const uint_t*)Ax + (size_t)(row0 + sar) * K + k0 + sak;
        uint4 a0 = *reinterpret_cast<const uint4*>(ap);
        uint4 a1 = *reinterpret_cast<const uint4*>(ap + 4);
        uint_t av[8] = {a0.x, a0.y, a0.z, a0.w, a1.x, a1.y, a1.z, a1.w};
#pragma unroll
        for (int j = 0; j < 8; ++j) {
          vh[j] = (short)(av[j] >> 16);
          vl[j] = (short)(av[j] & 0xffffu);
        }
      }
      *reinterpret_cast<short8v*>(&Ah[sar][sak]) = vh;
      *reinterpret_cast<short8v*>(&Al[sar][sak]) = vl;
    }
    {
      float bv[4];
#pragma unroll
      for (int j = 0; j < 4; ++j)
        bv[j] = B[(size_t)(k0 + sbk + j) * N + col0 + sbc];
      short4v vh, vl;
#pragma unroll
      for (int j = 0; j < 4; ++j) {
        ushort_t h, l; split_bf16(bv[j], h, l);
        vh[j] = (short)h; vl[j] = (short)l;
      }
      *reinterpret_cast<short4v*>(&Bh[sbc][sbk]) = vh;
      *reinterpret_cast<short4v*>(&Bl[sbc][sbk]) = vl;
    }
    __syncthreads();

    short8v ah[2], al[2], bh[2], bl[2];
#pragma unroll
    for (int i = 0; i < 2; ++i) {
      const int r = wm * 32 + i * 16 + l15;
      ah[i] = *reinterpret_cast<const short8v*>(&Ah[r][l16 * 8]);
      al[i] = *reinterpret_cast<const short8v*>(&Al[r][l16 * 8]);
    }
#pragma unroll
    for (int n = 0; n < 2; ++n) {
      const int c = wn * 32 + n * 16 + l15;
      bh[n] = *reinterpret_cast<const short8v*>(&Bh[c][l16 * 8]);
      bl[n] = *reinterpret_cast<const short8v*>(&Bl[c][l16 * 8]);
    }
#pragma unroll
    for (int i = 0; i < 2; ++i)
#pragma unroll
      for (int n = 0; n < 2; ++n) {
        acc[i][n] = __builtin_amdgcn_mfma_f32_16x16x32_bf16(ah[i], bh[n], acc[i][n], 0, 0, 0);
        acc[i][n] = __builtin_amdgcn_mfma_f32_16x16x32_bf16(ah[i], bl[n], acc[i][n], 0, 0, 0);
        acc[i][n] = __builtin_amdgcn_mfma_f32_16x16x32_bf16(al[i], bh[n], acc[i][n], 0, 0, 0);
      }
    __syncthreads();
  }

#pragma unroll
  for (int i = 0; i < 2; ++i) {
#pragma unroll
    for (int n = 0; n < 2; ++n) {
      const int col = col0 + wn * 32 + n * 16 + l15;
      float bs = BIAS ? bias[col] : 0.f;
#pragma unroll
      for (int r = 0; r < 4; ++r) {
        const int row = row0 + wm * 32 + i * 16 + l16 * 4 + r;
        float v = acc[i][n][r] + bs;
        if (RESID) v += resid[(size_t)row * N + col];
        if (RELU)  v = fmaxf(v, 0.f);
        if (PACKOUT) ((uint_t*)Cx)[(size_t)row * N + col] = pack_bf16(v);
        else         ((float*)Cx)[(size_t)row * N + col] = v;
      }
    }
  }
}

// ---------------- layernorm over HID=512, packed bf16-pair output ----------------
__global__ __launch_bounds__(64) void layernorm_k(
    const float* __restrict__ in, const float* __restrict__ g,
    const float* __restrict__ b, uint_t* __restrict__ out)
{
  const int row = blockIdx.x, lane = threadIdx.x;
  const float* p = in + (size_t)row * HID + lane * 8;
  float4 v0 = *reinterpret_cast<const float4*>(p);
  float4 v1 = *reinterpret_cast<const float4*>(p + 4);
  float s = v0.x + v0.y + v0.z + v0.w + v1.x + v1.y + v1.z + v1.w;
  s = rsum64(s);
  const float mean = s * (1.0f / HID);
  float x[8] = {v0.x, v0.y, v0.z, v0.w, v1.x, v1.y, v1.z, v1.w};
  float sq = 0.f;
#pragma unroll
  for (int j = 0; j < 8; ++j) { float d = x[j] - mean; sq += d * d; }
  sq = rsum64(sq);
  const float rstd = rsqrtf(sq * (1.0f / HID) + 1e-5f);
  float4 g0 = *reinterpret_cast<const float4*>(&g[lane * 8]);
  float4 g1 = *reinterpret_cast<const float4*>(&g[lane * 8 + 4]);
  float4 b0 = *reinterpret_cast<const float4*>(&b[lane * 8]);
  float4 b1 = *reinterpret_cast<const float4*>(&b[lane * 8 + 4]);
  float gg[8] = {g0.x, g0.y, g0.z, g0.w, g1.x, g1.y, g1.z, g1.w};
  float bb[8] = {b0.x, b0.y, b0.z, b0.w, b1.x, b1.y, b1.z, b1.w};
  uint_t o[8];
#pragma unroll
  for (int j = 0; j < 8; ++j) o[j] = pack_bf16((x[j] - mean) * rstd * gg[j] + bb[j]);
  uint4 o0 = make_uint4(o[0], o[1], o[2], o[3]);
  uint4 o1 = make_uint4(o[4], o[5], o[6], o[7]);
  uint_t* q = out + (size_t)row * HID + lane * 8;
  *reinterpret_cast<uint4*>(q) = o0;
  *reinterpret_cast<uint4*>(q + 4) = o1;
}

// ---- staggered matvec helpers: rotation R is a TEMPLATE constant, so all W/karr
// indices are compile-time after unrolling (R12's runtime-j spilled W to scratch).
template<int R>
__device__ __forceinline__ float dotA_rot(const float4* __restrict__ xv, const float* __restrict__ W){
  float a0=0.f,a1=0.f,a2=0.f,a3=0.f,a4=0.f,a5=0.f,a6=0.f,a7=0.f;
#pragma unroll
  for (int jj = 0; jj < 8; ++jj) {
    const int j = (jj + R) & 7;                    // compile-time per unrolled iter
    float4 x1 = xv[2*j], x2 = xv[2*j+1];
    a0 = fmaf(W[8*j+0], x1.x, a0);
    a1 = fmaf(W[8*j+1], x1.y, a1);
    a2 = fmaf(W[8*j+2], x1.z, a2);
    a3 = fmaf(W[8*j+3], x1.w, a3);
    a4 = fmaf(W[8*j+4], x2.x, a4);
    a5 = fmaf(W[8*j+5], x2.y, a5);
    a6 = fmaf(W[8*j+6], x2.z, a6);
    a7 = fmaf(W[8*j+7], x2.w, a7);
  }
  return ((a0 + a1) + (a2 + a3)) + ((a4 + a5) + (a6 + a7));
}

template<int R>
__device__ __forceinline__ float dotB_rot(const float4* __restrict__ qv, const float4* __restrict__ kv,
                                          float4* __restrict__ karr, const float* __restrict__ W){
  float a0=0.f,a1=0.f,a2=0.f,a3=0.f,a4=0.f,a5=0.f,a6=0.f,a7=0.f;
#pragma unroll
  for (int jj = 0; jj < 8; ++jj) {
    const int j = (jj + R) & 7;                    // compile-time per unrolled iter
    float4 q1 = qv[2*j], k1 = kv[2*j];
    float4 q2 = qv[2*j+1], k2 = kv[2*j+1];
    karr[2*j] = k1; karr[2*j+1] = k2;
    a0 = fmaf(W[8*j+0], q1.x - k1.x, a0);
    a1 = fmaf(W[8*j+1], q1.y - k1.y, a1);
    a2 = fmaf(W[8*j+2], q1.z - k1.z, a2);
    a3 = fmaf(W[8*j+3], q1.w - k1.w, a3);
    a4 = fmaf(W[8*j+4], q2.x - k2.x, a4);
    a5 = fmaf(W[8*j+5], q2.y - k2.y, a5);
    a6 = fmaf(W[8*j+6], q2.z - k2.z, a6);
    a7 = fmaf(W[8*j+7], q2.w - k2.w, a7);
  }
  return ((a0 + a1) + (a2 + a3)) + ((a4 + a5) + (a6 + a7));
}

// ---------------- fast-weight recurrence: 4 waves per chain, staggered LDS reads ----------------
// R9 srec4m (313us best) + per-wave COMPILE-TIME rotation of the post-barrier
// broadcast-read bursts (wave0 starts at quad 0, wave1 at quad 2, wave2 at quad 4),
// de-correlating the 3 simultaneous 16-quad LDS bursts on the CU's single LDS pipe.
// Wave-uniform branch selects the instantiation: no divergence, no runtime indexing.
__global__ __launch_bounds__(256) void srec4s2(
    const float* __restrict__ h,
    const float* __restrict__ Wy0, const float* __restrict__ Wq0,
    const float* __restrict__ Wk0, const float* __restrict__ wb0,
    uint_t* __restrict__ ys)
{
  const int bh = blockIdx.x;
  const int bb = bh >> 3, hh = bh & 7;
  const int tid = threadIdx.x;
  const int wv = tid >> 6, lane = tid & 63;

  __shared__ float xs[2][64];
  __shared__ float q_s[2][64];
  __shared__ float k_s[2][64];
  __shared__ float4 betas4[2];

  float W[64];
  float wbr[4] = {0.f, 0.f, 0.f, 0.f};
  float xrA = 0.f, xrB = 0.f;   // raw-x prefetch registers (alternating)
  float xnreg = 0.f;            // softmax(x(t+1)), carried interval -> interval

  const float* xp = h + (size_t)bb * HID + hh * 64 + lane;
  uint_t* yp = ys + (size_t)bb * HID + hh * 64 + lane;

  if (wv < 3) {
    const float* base = (wv == 0 ? Wy0 : (wv == 1 ? Wq0 : Wk0)) + (size_t)(hh * 64 + lane) * 64;
#pragma unroll
    for (int j = 0; j < 16; ++j) {
      float4 a = reinterpret_cast<const float4*>(base)[j];
      W[4*j] = a.x; W[4*j+1] = a.y; W[4*j+2] = a.z; W[4*j+3] = a.w;
    }
  } else {
    float4 w = *reinterpret_cast<const float4*>(&wb0[(size_t)(hh * 64 + lane) * 4]);
    wbr[0] = w.x; wbr[1] = w.y; wbr[2] = w.z; wbr[3] = w.w;
    float xr0 = xp[0];
    xrA = xp[(size_t)BSZ * HID];       // raw x(1)
    // softmax(x(0)) -> xs[0]   (no max-sub: shift-invariant)
    float e = __expf(xr0);
    float sm = rsum64(e);
    float x0 = e * __builtin_amdgcn_rcpf(sm);
    xs[0][lane] = x0;
    // betas for step 0
    float s0 = rsum64(wbr[0] * x0);
    float s1 = rsum64(wbr[1] * x0);
    float s2 = rsum64(wbr[2] * x0);
    float s3 = rsum64(wbr[3] * x0);
    if (lane == 0)
      betas4[0] = make_float4(__builtin_amdgcn_rcpf(1.f + __expf(-s0)),
                              __builtin_amdgcn_rcpf(1.f + __expf(-s1)),
                              __builtin_amdgcn_rcpf(1.f + __expf(-s2)),
                              __builtin_amdgcn_rcpf(1.f + __expf(-s3)));
  }
  SYNC_LDS();

  // ---- A-part of step T (phase parity P = T&1): matvec + softmax publish ----
  auto Apart = [&](int P, float& XCUR, float& XNEXT, int T) {
    if (wv == 3) {
      if (T + 2 < SLEN) XNEXT = xp[(size_t)(T + 2) * BSZ * HID];  // issue; used 2 intervals later
      // softmax of raw x(T+1) -> xs[1-P]   (no max-sub)
      float e = __expf(XCUR);
      float sm = rsum64(e);
      float xn_ = e * __builtin_amdgcn_rcpf(sm);
      xs[1 - P][lane] = xn_;
      xnreg = xn_;
    } else {
      const float4* xv = reinterpret_cast<const float4*>(xs[P]);
      float acc = (wv == 0) ? dotA_rot<0>(xv, W)
                : (wv == 1) ? dotA_rot<2>(xv, W)
                            : dotA_rot<4>(xv, W);
      if (wv == 0) {
        yp[(size_t)T * BSZ * HID] = pack_bf16(acc);   // fire-and-forget packed store
      } else {
        float e = __expf(acc);             // no max-sub
        float sm = rsum64(e);
        float v = e * __builtin_amdgcn_rcpf(sm);
        float* dst = (wv == 1) ? q_s[P] : k_s[P];
        dst[lane] = v;
      }
    }
  };

  // ---- B-part of step T (P = T&1): W/wb update + betas for step T+1 ----
  auto Bpart = [&](int P) {
    float4 bb4 = betas4[P];
    if (wv < 3) {
      const float4* qv = reinterpret_cast<const float4*>(q_s[P]);
      const float4* kv = reinterpret_cast<const float4*>(k_s[P]);
      float4 karr[16];
      float dd = (wv == 0) ? dotB_rot<0>(qv, kv, karr, W)
               : (wv == 1) ? dotB_rot<2>(qv, kv, karr, W)
                           : dotB_rot<4>(qv, kv, karr, W);
      float beta = (wv == 0) ? bb4.x : (wv == 1 ? bb4.y : bb4.z);
      float c = beta * dd;
#pragma unroll
      for (int j = 0; j < 16; ++j) {
        float4 k4 = karr[j];
        W[4*j]   = fmaf(c, k4.x, W[4*j]);
        W[4*j+1] = fmaf(c, k4.y, W[4*j+1]);
        W[4*j+2] = fmaf(c, k4.z, W[4*j+2]);
        W[4*j+3] = fmaf(c, k4.w, W[4*j+3]);
      }
    } else {
      // wb update + next-step betas via 9 INDEPENDENT reductions:
      // s_i(next) = (wbr_i + bk*d_i) . xn = rsum(wbr_i*xn) + d_i * rsum(bk*xn)
      float ql = q_s[P][lane], kl = k_s[P][lane];
      float dl = ql - kl;
      float bk = bb4.w * kl;
      float u0 = rsum64(wbr[0] * xnreg);
      float u1 = rsum64(wbr[1] * xnreg);
      float u2 = rsum64(wbr[2] * xnreg);
      float u3 = rsum64(wbr[3] * xnreg);
      float d0 = rsum64(wbr[0] * dl);
      float d1 = rsum64(wbr[1] * dl);
      float d2 = rsum64(wbr[2] * dl);
      float d3 = rsum64(wbr[3] * dl);
      float g  = rsum64(bk * xnreg);
      wbr[0] = fmaf(bk, d0, wbr[0]);
      wbr[1] = fmaf(bk, d1, wbr[1]);
      wbr[2] = fmaf(bk, d2, wbr[2]);
      wbr[3] = fmaf(bk, d3, wbr[3]);
      float s0 = fmaf(d0, g, u0);
      float s1 = fmaf(d1, g, u1);
      float s2 = fmaf(d2, g, u2);
      float s3 = fmaf(d3, g, u3);
      if (lane == 0)
        betas4[1 - P] = make_float4(__builtin_amdgcn_rcpf(1.f + __expf(-s0)),
                                    __builtin_amdgcn_rcpf(1.f + __expf(-s1)),
                                    __builtin_amdgcn_rcpf(1.f + __expf(-s2)),
                                    __builtin_amdgcn_rcpf(1.f + __expf(-s3)));
    }
  };

  // interval 0: A(0) only
  Apart(0, xrA, xrB, 0);
  SYNC_LDS();
  // intervals 1..254 (pairs): [B(t-1); A(t)] + one barrier each
  for (int t = 1; t < SLEN - 1; t += 2) {
    Bpart(0);  Apart(1, xrB, xrA, t);      SYNC_LDS();
    Bpart(1);  Apart(0, xrA, xrB, t + 1);  SYNC_LDS();
  }
  // final interval: B(254); A(255). Dead update B(255) skipped.
  Bpart(0);  Apart(1, xrB, xrA, SLEN - 1);
}

extern "C" void kernel_launch(void* const* d_in, const int* in_sizes, int n_in,
                              void* d_out, int out_size, void* d_ws, size_t ws_size,
                              hipStream_t stream)
{
  const float* x     = (const float*)d_in[0];
  const float* in_w  = (const float*)d_in[1];
  const float* in_b  = (const float*)d_in[2];
  const float* Wy    = (const float*)d_in[3];
  const float* Wq    = (const float*)d_in[4];
  const float* Wk    = (const float*)d_in[5];
  const float* wb    = (const float*)d_in[6];
  const float* Wout  = (const float*)d_in[7];
  const float* ln_g  = (const float*)d_in[8];
  const float* ln_b  = (const float*)d_in[9];
  const float* ff_w1 = (const float*)d_in[10];
  const float* ff_b1 = (const float*)d_in[11];
  const float* ff_w2 = (const float*)d_in[12];
  const float* ff_b2 = (const float*)d_in[13];
  float* out = (float*)d_out;

  char* ws = (char*)d_ws;
  uint_t* ys   = (uint_t*)ws;                  // 8MB  packed bf16-pair
  uint_t* ffb  = (uint_t*)(ws + (8u  << 20));  // 32MB packed
  uint_t* ybuf = (uint_t*)(ws + (40u << 20));  // 8MB  packed

  // ---- in-projection: A fp32 x, B fp32 in_w, C fp32 out. 256 blocks (full GPU). ----
  gemm64<HID, 512, 0, true, false, false, false><<<dim3(HID/64, MROWS/128), 512, 0, stream>>>(
      x, in_w, in_b, nullptr, out);

  for (int l = 0; l < 2; ++l) {
    srec4s2<<<128, 256, 0, stream>>>(out,
                                     Wy + (size_t)l * NH * HD * HD,
                                     Wq + (size_t)l * NH * HD * HD,
                                     Wk + (size_t)l * NH * HD * HD,
                                     wb + (size_t)l * NH * HD * 4,
                                     ys);
    // Wout: A packed ys, B fp32, resid fp32 out, C fp32 out. 256 blocks.
    gemm64<HID, HID, 1, false, true, false, false><<<dim3(HID/64, MROWS/128), 512, 0, stream>>>(
        ys, Wout + (size_t)l * HID * HID, nullptr, out, out);
    layernorm_k<<<MROWS, 64, 0, stream>>>(out, ln_g + (size_t)l * HID, ln_b + (size_t)l * HID, ybuf);
    // FF1: A packed ybuf, B fp32, relu, C packed ffb. 512 blocks (2/CU).
    gemm128<FFD, HID, 1, true, false, true, true><<<dim3(FFD/128, MROWS/128), 512, 0, stream>>>(
        ybuf, ff_w1 + (size_t)l * HID * FFD, ff_b1 + (size_t)l * FFD, nullptr, ffb);
    // FF2: A packed ffb, B fp32, resid fp32 out, C fp32 out. 256 blocks.
    gemm64<HID, FFD, 1, true, true, false, false><<<dim3(HID/64, MROWS/128), 512, 0, stream>>>(
        ffb, ff_w2 + (size_t)l * FFD * HID, ff_b2 + (size_t)l * HID, out, out);
  }
}

// Round 14
// 863.539 us; speedup vs baseline: 4.8124x; 1.0223x over previous
//
#include <hip/hip_runtime.h>
#include <hip/hip_bf16.h>
#include <math.h>

#define SLEN 256
#define BSZ  16
#define NH   8
#define HD   64
#define HID  512
#define FFD  2048
#define MROWS (SLEN*BSZ)   // 4096

typedef __attribute__((ext_vector_type(8))) short short8v;
typedef __attribute__((ext_vector_type(4))) short short4v;
typedef __attribute__((ext_vector_type(4))) float float4v;
typedef unsigned short ushort_t;
typedef unsigned int uint_t;

// lgkmcnt-only barrier: LDS visibility without draining vmcnt.
#define SYNC_LDS() do { \
  asm volatile("s_waitcnt lgkmcnt(0)" ::: "memory"); \
  __builtin_amdgcn_s_barrier(); \
} while (0)

// ---- all-VALU wave-64 reductions: 4 DPP xor levels + row_bcast15/31 + readlane ----
template<int C> __device__ __forceinline__ float dppf(float x){
  return __int_as_float(__builtin_amdgcn_update_dpp(__float_as_int(x), __float_as_int(x), C, 0xF, 0xF, false));
}

__device__ __forceinline__ float rsum64(float v){
  v += dppf<0xB1>(v);   // xor 1
  v += dppf<0x4E>(v);   // xor 2
  v += dppf<0x141>(v);  // row_half_mirror (xor 4 level)
  v += dppf<0x140>(v);  // row_mirror      (xor 8 level)
  v += __int_as_float(__builtin_amdgcn_update_dpp(0, __float_as_int(v), 0x142, 0xa, 0xF, false)); // bcast15
  v += __int_as_float(__builtin_amdgcn_update_dpp(0, __float_as_int(v), 0x143, 0xc, 0xF, false)); // bcast31
  return __int_as_float(__builtin_amdgcn_readlane(__float_as_int(v), 63));
}

__device__ __forceinline__ void split_bf16(float f, ushort_t& h, ushort_t& l){
  unsigned u = __float_as_uint(f);
  unsigned r = u + (0x7fffu + ((u >> 16) & 1u));
  h = (ushort_t)(r >> 16);
  float hf = __uint_as_float(((unsigned)h) << 16);
  float lo = f - hf;
  unsigned u2 = __float_as_uint(lo);
  unsigned r2 = u2 + (0x7fffu + ((u2 >> 16) & 1u));
  l = (ushort_t)(r2 >> 16);
}

__device__ __forceinline__ uint_t pack_bf16(float f){
  ushort_t h, l; split_bf16(f, h, l);
  return ((uint_t)h << 16) | (uint_t)l;
}

// ---------------- MFMA GEMM, bf16x3 split, BN=128 tile (for N=2048) ----------------
template<int N, int K, int AMODE, bool BIAS, bool RESID, bool RELU, bool PACKOUT>
__global__ __launch_bounds__(512) void gemm128(
    const void* __restrict__ Ax, const float* __restrict__ B,
    const float* __restrict__ bias, const float* __restrict__ resid,
    void* __restrict__ Cx)
{
  __shared__ ushort_t Ah[128][40];
  __shared__ ushort_t Al[128][40];
  __shared__ ushort_t Bh[128][40];   // [col][k]
  __shared__ ushort_t Bl[128][40];

  const int tid = threadIdx.x;
  const int wv = tid >> 6, lane = tid & 63;
  const int wm = wv >> 2, wn = wv & 3;
  const int l15 = lane & 15, l16 = lane >> 4;
  const int row0 = blockIdx.y * 128, col0 = blockIdx.x * 128;

  const int sar = tid >> 2, sak = (tid & 3) * 8;
  const int sbc = tid & 127, sbk = (tid >> 7) * 8;

  float4v acc[4][2];
#pragma unroll
  for (int i = 0; i < 4; ++i)
#pragma unroll
    for (int n = 0; n < 2; ++n) acc[i][n] = (float4v)(0.f);

  for (int k0 = 0; k0 < K; k0 += 32) {
    {
      short8v vh, vl;
      if (AMODE == 0) {
        const float* ap = (const float*)Ax + (size_t)(row0 + sar) * K + k0 + sak;
        float4 a0 = *reinterpret_cast<const float4*>(ap);
        float4 a1 = *reinterpret_cast<const float4*>(ap + 4);
        float av[8] = {a0.x, a0.y, a0.z, a0.w, a1.x, a1.y, a1.z, a1.w};
#pragma unroll
        for (int j = 0; j < 8; ++j) {
          ushort_t h, l; split_bf16(av[j], h, l);
          vh[j] = (short)h; vl[j] = (short)l;
        }
      } else {
        const uint_t* ap = (const uint_t*)Ax + (size_t)(row0 + sar) * K + k0 + sak;
        uint4 a0 = *reinterpret_cast<const uint4*>(ap);
        uint4 a1 = *reinterpret_cast<const uint4*>(ap + 4);
        uint_t av[8] = {a0.x, a0.y, a0.z, a0.w, a1.x, a1.y, a1.z, a1.w};
#pragma unroll
        for (int j = 0; j < 8; ++j) {
          vh[j] = (short)(av[j] >> 16);
          vl[j] = (short)(av[j] & 0xffffu);
        }
      }
      *reinterpret_cast<short8v*>(&Ah[sar][sak]) = vh;
      *reinterpret_cast<short8v*>(&Al[sar][sak]) = vl;
    }
    {
      float bv[8];
#pragma unroll
      for (int j = 0; j < 8; ++j)
        bv[j] = B[(size_t)(k0 + sbk + j) * N + col0 + sbc];
      short8v vh, vl;
#pragma unroll
      for (int j = 0; j < 8; ++j) {
        ushort_t h, l; split_bf16(bv[j], h, l);
        vh[j] = (short)h; vl[j] = (short)l;
      }
      *reinterpret_cast<short8v*>(&Bh[sbc][sbk]) = vh;
      *reinterpret_cast<short8v*>(&Bl[sbc][sbk]) = vl;
    }
    __syncthreads();

    short8v ah[4], al[4], bh[2], bl[2];
#pragma unroll
    for (int i = 0; i < 4; ++i) {
      const int r = wm * 64 + i * 16 + l15;
      ah[i] = *reinterpret_cast<const short8v*>(&Ah[r][l16 * 8]);
      al[i] = *reinterpret_cast<const short8v*>(&Al[r][l16 * 8]);
    }
#pragma unroll
    for (int n = 0; n < 2; ++n) {
      const int c = wn * 32 + n * 16 + l15;
      bh[n] = *reinterpret_cast<const short8v*>(&Bh[c][l16 * 8]);
      bl[n] = *reinterpret_cast<const short8v*>(&Bl[c][l16 * 8]);
    }
#pragma unroll
    for (int i = 0; i < 4; ++i)
#pragma unroll
      for (int n = 0; n < 2; ++n) {
        acc[i][n] = __builtin_amdgcn_mfma_f32_16x16x32_bf16(ah[i], bh[n], acc[i][n], 0, 0, 0);
        acc[i][n] = __builtin_amdgcn_mfma_f32_16x16x32_bf16(ah[i], bl[n], acc[i][n], 0, 0, 0);
        acc[i][n] = __builtin_amdgcn_mfma_f32_16x16x32_bf16(al[i], bh[n], acc[i][n], 0, 0, 0);
      }
    __syncthreads();
  }

#pragma unroll
  for (int i = 0; i < 4; ++i) {
#pragma unroll
    for (int n = 0; n < 2; ++n) {
      const int col = col0 + wn * 32 + n * 16 + l15;
      float bs = BIAS ? bias[col] : 0.f;
#pragma unroll
      for (int r = 0; r < 4; ++r) {
        const int row = row0 + wm * 64 + i * 16 + l16 * 4 + r;
        float v = acc[i][n][r] + bs;
        if (RESID) v += resid[(size_t)row * N + col];
        if (RELU)  v = fmaxf(v, 0.f);
        if (PACKOUT) ((uint_t*)Cx)[(size_t)row * N + col] = pack_bf16(v);
        else         ((float*)Cx)[(size_t)row * N + col] = v;
      }
    }
  }
}

// ---------------- MFMA GEMM, bf16x3 split, BN=64 tile (for N=512) ----------------
// 128x64 tile -> 256 blocks for N=512: full GPU. 8 waves as 4(row)x2(col).
template<int N, int K, int AMODE, bool BIAS, bool RESID, bool RELU, bool PACKOUT>
__global__ __launch_bounds__(512) void gemm64(
    const void* __restrict__ Ax, const float* __restrict__ B,
    const float* __restrict__ bias, const float* __restrict__ resid,
    void* __restrict__ Cx)
{
  __shared__ ushort_t Ah[128][40];
  __shared__ ushort_t Al[128][40];
  __shared__ ushort_t Bh[64][40];   // [col][k]
  __shared__ ushort_t Bl[64][40];

  const int tid = threadIdx.x;
  const int wv = tid >> 6, lane = tid & 63;
  const int wm = wv >> 1;          // 0..3 : 32-row band
  const int wn = wv & 1;           // 0..1 : 32-col half
  const int l15 = lane & 15, l16 = lane >> 4;
  const int row0 = blockIdx.y * 128, col0 = blockIdx.x * 64;

  const int sar = tid >> 2, sak = (tid & 3) * 8;    // A: 128r x 32k, 8/thread
  const int sbc = tid & 63,  sbk = (tid >> 6) * 4;  // B: 64c x 32k, 4/thread

  float4v acc[2][2];
#pragma unroll
  for (int i = 0; i < 2; ++i)
#pragma unroll
    for (int n = 0; n < 2; ++n) acc[i][n] = (float4v)(0.f);

  for (int k0 = 0; k0 < K; k0 += 32) {
    {
      short8v vh, vl;
      if (AMODE == 0) {
        const float* ap = (const float*)Ax + (size_t)(row0 + sar) * K + k0 + sak;
        float4 a0 = *reinterpret_cast<const float4*>(ap);
        float4 a1 = *reinterpret_cast<const float4*>(ap + 4);
        float av[8] = {a0.x, a0.y, a0.z, a0.w, a1.x, a1.y, a1.z, a1.w};
#pragma unroll
        for (int j = 0; j < 8; ++j) {
          ushort_t h, l; split_bf16(av[j], h, l);
          vh[j] = (short)h; vl[j] = (short)l;
        }
      } else {
        const uint_t* ap = (const uint_t*)Ax + (size_t)(row0 + sar) * K + k0 + sak;
        uint4 a0 = *reinterpret_cast<const uint4*>(ap);
        uint4 a1 = *reinterpret_cast<const uint4*>(ap + 4);
        uint_t av[8] = {a0.x, a0.y, a0.z, a0.w, a1.x, a1.y, a1.z, a1.w};
#pragma unroll
        for (int j = 0; j < 8; ++j) {
          vh[j] = (short)(av[j] >> 16);
          vl[j] = (short)(av[j] & 0xffffu);
        }
      }
      *reinterpret_cast<short8v*>(&Ah[sar][sak]) = vh;
      *reinterpret_cast<short8v*>(&Al[sar][sak]) = vl;
    }
    {
      float bv[4];
#pragma unroll
      for (int j = 0; j < 4; ++j)
        bv[j] = B[(size_t)(k0 + sbk + j) * N + col0 + sbc];
      short4v vh, vl;
#pragma unroll
      for (int j = 0; j < 4; ++j) {
        ushort_t h, l; split_bf16(bv[j], h, l);
        vh[j] = (short)h; vl[j] = (short)l;
      }
      *reinterpret_cast<short4v*>(&Bh[sbc][sbk]) = vh;
      *reinterpret_cast<short4v*>(&Bl[sbc][sbk]) = vl;
    }
    __syncthreads();

    short8v ah[2], al[2], bh[2], bl[2];
#pragma unroll
    for (int i = 0; i < 2; ++i) {
      const int r = wm * 32 + i * 16 + l15;
      ah[i] = *reinterpret_cast<const short8v*>(&Ah[r][l16 * 8]);
      al[i] = *reinterpret_cast<const short8v*>(&Al[r][l16 * 8]);
    }
#pragma unroll
    for (int n = 0; n < 2; ++n) {
      const int c = wn * 32 + n * 16 + l15;
      bh[n] = *reinterpret_cast<const short8v*>(&Bh[c][l16 * 8]);
      bl[n] = *reinterpret_cast<const short8v*>(&Bl[c][l16 * 8]);
    }
#pragma unroll
    for (int i = 0; i < 2; ++i)
#pragma unroll
      for (int n = 0; n < 2; ++n) {
        acc[i][n] = __builtin_amdgcn_mfma_f32_16x16x32_bf16(ah[i], bh[n], acc[i][n], 0, 0, 0);
        acc[i][n] = __builtin_amdgcn_mfma_f32_16x16x32_bf16(ah[i], bl[n], acc[i][n], 0, 0, 0);
        acc[i][n] = __builtin_amdgcn_mfma_f32_16x16x32_bf16(al[i], bh[n], acc[i][n], 0, 0, 0);
      }
    __syncthreads();
  }

#pragma unroll
  for (int i = 0; i < 2; ++i) {
#pragma unroll
    for (int n = 0; n < 2; ++n) {
      const int col = col0 + wn * 32 + n * 16 + l15;
      float bs = BIAS ? bias[col] : 0.f;
#pragma unroll
      for (int r = 0; r < 4; ++r) {
        const int row = row0 + wm * 32 + i * 16 + l16 * 4 + r;
        float v = acc[i][n][r] + bs;
        if (RESID) v += resid[(size_t)row * N + col];
        if (RELU)  v = fmaxf(v, 0.f);
        if (PACKOUT) ((uint_t*)Cx)[(size_t)row * N + col] = pack_bf16(v);
        else         ((float*)Cx)[(size_t)row * N + col] = v;
      }
    }
  }
}

// ---------------- layernorm over HID=512, packed bf16-pair output ----------------
__global__ __launch_bounds__(64) void layernorm_k(
    const float* __restrict__ in, const float* __restrict__ g,
    const float* __restrict__ b, uint_t* __restrict__ out)
{
  const int row = blockIdx.x, lane = threadIdx.x;
  const float* p = in + (size_t)row * HID + lane * 8;
  float4 v0 = *reinterpret_cast<const float4*>(p);
  float4 v1 = *reinterpret_cast<const float4*>(p + 4);
  float s = v0.x + v0.y + v0.z + v0.w + v1.x + v1.y + v1.z + v1.w;
  s = rsum64(s);
  const float mean = s * (1.0f / HID);
  float x[8] = {v0.x, v0.y, v0.z, v0.w, v1.x, v1.y, v1.z, v1.w};
  float sq = 0.f;
#pragma unroll
  for (int j = 0; j < 8; ++j) { float d = x[j] - mean; sq += d * d; }
  sq = rsum64(sq);
  const float rstd = rsqrtf(sq * (1.0f / HID) + 1e-5f);
  float4 g0 = *reinterpret_cast<const float4*>(&g[lane * 8]);
  float4 g1 = *reinterpret_cast<const float4*>(&g[lane * 8 + 4]);
  float4 b0 = *reinterpret_cast<const float4*>(&b[lane * 8]);
  float4 b1 = *reinterpret_cast<const float4*>(&b[lane * 8 + 4]);
  float gg[8] = {g0.x, g0.y, g0.z, g0.w, g1.x, g1.y, g1.z, g1.w};
  float bb[8] = {b0.x, b0.y, b0.z, b0.w, b1.x, b1.y, b1.z, b1.w};
  uint_t o[8];
#pragma unroll
  for (int j = 0; j < 8; ++j) o[j] = pack_bf16((x[j] - mean) * rstd * gg[j] + bb[j]);
  uint4 o0 = make_uint4(o[0], o[1], o[2], o[3]);
  uint4 o1 = make_uint4(o[4], o[5], o[6], o[7]);
  uint_t* q = out + (size_t)row * HID + lane * 8;
  *reinterpret_cast<uint4*>(q) = o0;
  *reinterpret_cast<uint4*>(q + 4) = o1;
}

// ---------------- fast-weight recurrence: 4 waves per (b,h) chain, 1 barrier/step ----------------
// Session-best srec (R9, 313us/dispatch): merged interval [B(t-1); A(t)] + ONE
// barrier per step (halved barrier count; safe because W is wave-private and all
// cross-wave LDS is double-buffered across the barrier), no max-sub softmax
// (shift-invariant), wave3's 9 reductions fully independent, rcp sigmoid,
// 8-accumulator matvecs, packed-bf16 y store, dead final update skipped.
// Established floor: DPP ~14% (R10 ablation), exp ~0, barriers ~2%, LDS
// throughput/burst ~0 (R4/R11/R13) — remainder is irreducible dependency
// latency at 1 wave/SIMD.
__global__ __launch_bounds__(256) void srec4m(
    const float* __restrict__ h,
    const float* __restrict__ Wy0, const float* __restrict__ Wq0,
    const float* __restrict__ Wk0, const float* __restrict__ wb0,
    uint_t* __restrict__ ys)
{
  const int bh = blockIdx.x;
  const int bb = bh >> 3, hh = bh & 7;
  const int tid = threadIdx.x;
  const int wv = tid >> 6, lane = tid & 63;

  __shared__ float xs[2][64];
  __shared__ float q_s[2][64];
  __shared__ float k_s[2][64];
  __shared__ float4 betas4[2];

  float W[64];
  float wbr[4] = {0.f, 0.f, 0.f, 0.f};
  float xrA = 0.f, xrB = 0.f;   // raw-x prefetch registers (alternating)
  float xnreg = 0.f;            // softmax(x(t+1)), carried interval -> interval

  const float* xp = h + (size_t)bb * HID + hh * 64 + lane;
  uint_t* yp = ys + (size_t)bb * HID + hh * 64 + lane;

  if (wv < 3) {
    const float* base = (wv == 0 ? Wy0 : (wv == 1 ? Wq0 : Wk0)) + (size_t)(hh * 64 + lane) * 64;
#pragma unroll
    for (int j = 0; j < 16; ++j) {
      float4 a = reinterpret_cast<const float4*>(base)[j];
      W[4*j] = a.x; W[4*j+1] = a.y; W[4*j+2] = a.z; W[4*j+3] = a.w;
    }
  } else {
    float4 w = *reinterpret_cast<const float4*>(&wb0[(size_t)(hh * 64 + lane) * 4]);
    wbr[0] = w.x; wbr[1] = w.y; wbr[2] = w.z; wbr[3] = w.w;
    float xr0 = xp[0];
    xrA = xp[(size_t)BSZ * HID];       // raw x(1)
    // softmax(x(0)) -> xs[0]   (no max-sub: shift-invariant)
    float e = __expf(xr0);
    float sm = rsum64(e);
    float x0 = e * __builtin_amdgcn_rcpf(sm);
    xs[0][lane] = x0;
    // betas for step 0
    float s0 = rsum64(wbr[0] * x0);
    float s1 = rsum64(wbr[1] * x0);
    float s2 = rsum64(wbr[2] * x0);
    float s3 = rsum64(wbr[3] * x0);
    if (lane == 0)
      betas4[0] = make_float4(__builtin_amdgcn_rcpf(1.f + __expf(-s0)),
                              __builtin_amdgcn_rcpf(1.f + __expf(-s1)),
                              __builtin_amdgcn_rcpf(1.f + __expf(-s2)),
                              __builtin_amdgcn_rcpf(1.f + __expf(-s3)));
  }
  SYNC_LDS();

  // ---- A-part of step T (phase parity P = T&1): matvec + softmax publish ----
  auto Apart = [&](int P, float& XCUR, float& XNEXT, int T) {
    if (wv == 3) {
      if (T + 2 < SLEN) XNEXT = xp[(size_t)(T + 2) * BSZ * HID];  // issue; used 2 intervals later
      // softmax of raw x(T+1) -> xs[1-P]   (no max-sub)
      float e = __expf(XCUR);
      float sm = rsum64(e);
      float xn_ = e * __builtin_amdgcn_rcpf(sm);
      xs[1 - P][lane] = xn_;
      xnreg = xn_;
    } else {
      const float4* xv = reinterpret_cast<const float4*>(xs[P]);
      float a0=0.f,a1=0.f,a2=0.f,a3=0.f,a4=0.f,a5=0.f,a6=0.f,a7=0.f;
#pragma unroll
      for (int j = 0; j < 8; ++j) {
        float4 x1 = xv[2*j], x2 = xv[2*j+1];
        a0 = fmaf(W[8*j+0], x1.x, a0);
        a1 = fmaf(W[8*j+1], x1.y, a1);
        a2 = fmaf(W[8*j+2], x1.z, a2);
        a3 = fmaf(W[8*j+3], x1.w, a3);
        a4 = fmaf(W[8*j+4], x2.x, a4);
        a5 = fmaf(W[8*j+5], x2.y, a5);
        a6 = fmaf(W[8*j+6], x2.z, a6);
        a7 = fmaf(W[8*j+7], x2.w, a7);
      }
      float acc = ((a0 + a1) + (a2 + a3)) + ((a4 + a5) + (a6 + a7));
      if (wv == 0) {
        yp[(size_t)T * BSZ * HID] = pack_bf16(acc);   // fire-and-forget packed store
      } else {
        float e = __expf(acc);             // no max-sub
        float sm = rsum64(e);
        float v = e * __builtin_amdgcn_rcpf(sm);
        float* dst = (wv == 1) ? q_s[P] : k_s[P];
        dst[lane] = v;
      }
    }
  };

  // ---- B-part of step T (P = T&1): W/wb update + betas for step T+1 ----
  auto Bpart = [&](int P) {
    float4 bb4 = betas4[P];
    if (wv < 3) {
      const float4* qv = reinterpret_cast<const float4*>(q_s[P]);
      const float4* kv = reinterpret_cast<const float4*>(k_s[P]);
      float4 karr[16];
      float a0=0.f,a1=0.f,a2=0.f,a3=0.f,a4=0.f,a5=0.f,a6=0.f,a7=0.f;
#pragma unroll
      for (int j = 0; j < 8; ++j) {
        float4 q1 = qv[2*j], k1 = kv[2*j];
        float4 q2 = qv[2*j+1], k2 = kv[2*j+1];
        karr[2*j] = k1; karr[2*j+1] = k2;
        a0 = fmaf(W[8*j+0], q1.x - k1.x, a0);
        a1 = fmaf(W[8*j+1], q1.y - k1.y, a1);
        a2 = fmaf(W[8*j+2], q1.z - k1.z, a2);
        a3 = fmaf(W[8*j+3], q1.w - k1.w, a3);
        a4 = fmaf(W[8*j+4], q2.x - k2.x, a4);
        a5 = fmaf(W[8*j+5], q2.y - k2.y, a5);
        a6 = fmaf(W[8*j+6], q2.z - k2.z, a6);
        a7 = fmaf(W[8*j+7], q2.w - k2.w, a7);
      }
      float dd = ((a0 + a1) + (a2 + a3)) + ((a4 + a5) + (a6 + a7));
      float beta = (wv == 0) ? bb4.x : (wv == 1 ? bb4.y : bb4.z);
      float c = beta * dd;
#pragma unroll
      for (int j = 0; j < 16; ++j) {
        float4 k4 = karr[j];
        W[4*j]   = fmaf(c, k4.x, W[4*j]);
        W[4*j+1] = fmaf(c, k4.y, W[4*j+1]);
        W[4*j+2] = fmaf(c, k4.z, W[4*j+2]);
        W[4*j+3] = fmaf(c, k4.w, W[4*j+3]);
      }
    } else {
      // wb update + next-step betas via 9 INDEPENDENT reductions:
      // s_i(next) = (wbr_i + bk*d_i) . xn = rsum(wbr_i*xn) + d_i * rsum(bk*xn)
      float ql = q_s[P][lane], kl = k_s[P][lane];
      float dl = ql - kl;
      float bk = bb4.w * kl;
      float u0 = rsum64(wbr[0] * xnreg);
      float u1 = rsum64(wbr[1] * xnreg);
      float u2 = rsum64(wbr[2] * xnreg);
      float u3 = rsum64(wbr[3] * xnreg);
      float d0 = rsum64(wbr[0] * dl);
      float d1 = rsum64(wbr[1] * dl);
      float d2 = rsum64(wbr[2] * dl);
      float d3 = rsum64(wbr[3] * dl);
      float g  = rsum64(bk * xnreg);
      wbr[0] = fmaf(bk, d0, wbr[0]);
      wbr[1] = fmaf(bk, d1, wbr[1]);
      wbr[2] = fmaf(bk, d2, wbr[2]);
      wbr[3] = fmaf(bk, d3, wbr[3]);
      float s0 = fmaf(d0, g, u0);
      float s1 = fmaf(d1, g, u1);
      float s2 = fmaf(d2, g, u2);
      float s3 = fmaf(d3, g, u3);
      if (lane == 0)
        betas4[1 - P] = make_float4(__builtin_amdgcn_rcpf(1.f + __expf(-s0)),
                                    __builtin_amdgcn_rcpf(1.f + __expf(-s1)),
                                    __builtin_amdgcn_rcpf(1.f + __expf(-s2)),
                                    __builtin_amdgcn_rcpf(1.f + __expf(-s3)));
    }
  };

  // interval 0: A(0) only
  Apart(0, xrA, xrB, 0);
  SYNC_LDS();
  // intervals 1..254 (pairs): [B(t-1); A(t)] + one barrier each
  for (int t = 1; t < SLEN - 1; t += 2) {
    Bpart(0);  Apart(1, xrB, xrA, t);      SYNC_LDS();
    Bpart(1);  Apart(0, xrA, xrB, t + 1);  SYNC_LDS();
  }
  // final interval: B(254); A(255). Dead update B(255) skipped.
  Bpart(0);  Apart(1, xrB, xrA, SLEN - 1);
}

extern "C" void kernel_launch(void* const* d_in, const int* in_sizes, int n_in,
                              void* d_out, int out_size, void* d_ws, size_t ws_size,
                              hipStream_t stream)
{
  const float* x     = (const float*)d_in[0];
  const float* in_w  = (const float*)d_in[1];
  const float* in_b  = (const float*)d_in[2];
  const float* Wy    = (const float*)d_in[3];
  const float* Wq    = (const float*)d_in[4];
  const float* Wk    = (const float*)d_in[5];
  const float* wb    = (const float*)d_in[6];
  const float* Wout  = (const float*)d_in[7];
  const float* ln_g  = (const float*)d_in[8];
  const float* ln_b  = (const float*)d_in[9];
  const float* ff_w1 = (const float*)d_in[10];
  const float* ff_b1 = (const float*)d_in[11];
  const float* ff_w2 = (const float*)d_in[12];
  const float* ff_b2 = (const float*)d_in[13];
  float* out = (float*)d_out;

  char* ws = (char*)d_ws;
  uint_t* ys   = (uint_t*)ws;                  // 8MB  packed bf16-pair
  uint_t* ffb  = (uint_t*)(ws + (8u  << 20));  // 32MB packed
  uint_t* ybuf = (uint_t*)(ws + (40u << 20));  // 8MB  packed

  // ---- in-projection: A fp32 x, B fp32 in_w, C fp32 out. 256 blocks (full GPU). ----
  gemm64<HID, 512, 0, true, false, false, false><<<dim3(HID/64, MROWS/128), 512, 0, stream>>>(
      x, in_w, in_b, nullptr, out);

  for (int l = 0; l < 2; ++l) {
    srec4m<<<128, 256, 0, stream>>>(out,
                                    Wy + (size_t)l * NH * HD * HD,
                                    Wq + (size_t)l * NH * HD * HD,
                                    Wk + (size_t)l * NH * HD * HD,
                                    wb + (size_t)l * NH * HD * 4,
                                    ys);
    // Wout: A packed ys, B fp32, resid fp32 out, C fp32 out. 256 blocks.
    gemm64<HID, HID, 1, false, true, false, false><<<dim3(HID/64, MROWS/128), 512, 0, stream>>>(
        ys, Wout + (size_t)l * HID * HID, nullptr, out, out);
    layernorm_k<<<MROWS, 64, 0, stream>>>(out, ln_g + (size_t)l * HID, ln_b + (size_t)l * HID, ybuf);
    // FF1: A packed ybuf, B fp32, relu, C packed ffb. 512 blocks (2/CU).
    gemm128<FFD, HID, 1, true, false, true, true><<<dim3(FFD/128, MROWS/128), 512, 0, stream>>>(
        ybuf, ff_w1 + (size_t)l * HID * FFD, ff_b1 + (size_t)l * FFD, nullptr, ffb);
    // FF2: A packed ffb, B fp32, resid fp32 out, C fp32 out. 256 blocks.
    gemm64<HID, FFD, 1, true, true, false, false><<<dim3(HID/64, MROWS/128), 512, 0, stream>>>(
        ffb, ff_w2 + (size_t)l * FFD * HID, ff_b2 + (size_t)l * HID, out, out);
  }
}

// Round 15
// 844.817 us; speedup vs baseline: 4.9190x; 1.0222x over previous
//
#include <hip/hip_runtime.h>
#include <hip/hip_bf16.h>
#include <math.h>

#define SLEN 256
#define BSZ  16
#define NH   8
#define HD   64
#define HID  512
#define FFD  2048
#define MROWS (SLEN*BSZ)   // 4096

typedef __attribute__((ext_vector_type(8))) short short8v;
typedef __attribute__((ext_vector_type(4))) short short4v;
typedef __attribute__((ext_vector_type(4))) float float4v;
typedef unsigned short ushort_t;
typedef unsigned int uint_t;

// lgkmcnt-only barrier: LDS visibility without draining vmcnt.
#define SYNC_LDS() do { \
  asm volatile("s_waitcnt lgkmcnt(0)" ::: "memory"); \
  __builtin_amdgcn_s_barrier(); \
} while (0)

// ---- all-VALU wave-64 reductions: 4 DPP xor levels + row_bcast15/31 + readlane ----
template<int C> __device__ __forceinline__ float dppf(float x){
  return __int_as_float(__builtin_amdgcn_update_dpp(__float_as_int(x), __float_as_int(x), C, 0xF, 0xF, false));
}

__device__ __forceinline__ float rsum64(float v){
  v += dppf<0xB1>(v);   // xor 1
  v += dppf<0x4E>(v);   // xor 2
  v += dppf<0x141>(v);  // row_half_mirror (xor 4 level)
  v += dppf<0x140>(v);  // row_mirror      (xor 8 level)
  v += __int_as_float(__builtin_amdgcn_update_dpp(0, __float_as_int(v), 0x142, 0xa, 0xF, false)); // bcast15
  v += __int_as_float(__builtin_amdgcn_update_dpp(0, __float_as_int(v), 0x143, 0xc, 0xF, false)); // bcast31
  return __int_as_float(__builtin_amdgcn_readlane(__float_as_int(v), 63));
}

__device__ __forceinline__ void split_bf16(float f, ushort_t& h, ushort_t& l){
  unsigned u = __float_as_uint(f);
  unsigned r = u + (0x7fffu + ((u >> 16) & 1u));
  h = (ushort_t)(r >> 16);
  float hf = __uint_as_float(((unsigned)h) << 16);
  float lo = f - hf;
  unsigned u2 = __float_as_uint(lo);
  unsigned r2 = u2 + (0x7fffu + ((u2 >> 16) & 1u));
  l = (ushort_t)(r2 >> 16);
}

__device__ __forceinline__ uint_t pack_bf16(float f){
  ushort_t h, l; split_bf16(f, h, l);
  return ((uint_t)h << 16) | (uint_t)l;
}

// ---------------- MFMA GEMM, bf16x3 split, BN=128 tile (for N=2048 / FF1) ----------------
template<int N, int K, int AMODE, bool BIAS, bool RESID, bool RELU, bool PACKOUT>
__global__ __launch_bounds__(512) void gemm128(
    const void* __restrict__ Ax, const float* __restrict__ B,
    const float* __restrict__ bias, const float* __restrict__ resid,
    void* __restrict__ Cx)
{
  __shared__ ushort_t Ah[128][40];
  __shared__ ushort_t Al[128][40];
  __shared__ ushort_t Bh[128][40];   // [col][k]
  __shared__ ushort_t Bl[128][40];

  const int tid = threadIdx.x;
  const int wv = tid >> 6, lane = tid & 63;
  const int wm = wv >> 2, wn = wv & 3;
  const int l15 = lane & 15, l16 = lane >> 4;
  const int row0 = blockIdx.y * 128, col0 = blockIdx.x * 128;

  const int sar = tid >> 2, sak = (tid & 3) * 8;
  const int sbc = tid & 127, sbk = (tid >> 7) * 8;

  float4v acc[4][2];
#pragma unroll
  for (int i = 0; i < 4; ++i)
#pragma unroll
    for (int n = 0; n < 2; ++n) acc[i][n] = (float4v)(0.f);

  for (int k0 = 0; k0 < K; k0 += 32) {
    {
      short8v vh, vl;
      if (AMODE == 0) {
        const float* ap = (const float*)Ax + (size_t)(row0 + sar) * K + k0 + sak;
        float4 a0 = *reinterpret_cast<const float4*>(ap);
        float4 a1 = *reinterpret_cast<const float4*>(ap + 4);
        float av[8] = {a0.x, a0.y, a0.z, a0.w, a1.x, a1.y, a1.z, a1.w};
#pragma unroll
        for (int j = 0; j < 8; ++j) {
          ushort_t h, l; split_bf16(av[j], h, l);
          vh[j] = (short)h; vl[j] = (short)l;
        }
      } else {
        const uint_t* ap = (const uint_t*)Ax + (size_t)(row0 + sar) * K + k0 + sak;
        uint4 a0 = *reinterpret_cast<const uint4*>(ap);
        uint4 a1 = *reinterpret_cast<const uint4*>(ap + 4);
        uint_t av[8] = {a0.x, a0.y, a0.z, a0.w, a1.x, a1.y, a1.z, a1.w};
#pragma unroll
        for (int j = 0; j < 8; ++j) {
          vh[j] = (short)(av[j] >> 16);
          vl[j] = (short)(av[j] & 0xffffu);
        }
      }
      *reinterpret_cast<short8v*>(&Ah[sar][sak]) = vh;
      *reinterpret_cast<short8v*>(&Al[sar][sak]) = vl;
    }
    {
      float bv[8];
#pragma unroll
      for (int j = 0; j < 8; ++j)
        bv[j] = B[(size_t)(k0 + sbk + j) * N + col0 + sbc];
      short8v vh, vl;
#pragma unroll
      for (int j = 0; j < 8; ++j) {
        ushort_t h, l; split_bf16(bv[j], h, l);
        vh[j] = (short)h; vl[j] = (short)l;
      }
      *reinterpret_cast<short8v*>(&Bh[sbc][sbk]) = vh;
      *reinterpret_cast<short8v*>(&Bl[sbc][sbk]) = vl;
    }
    __syncthreads();

    short8v ah[4], al[4], bh[2], bl[2];
#pragma unroll
    for (int i = 0; i < 4; ++i) {
      const int r = wm * 64 + i * 16 + l15;
      ah[i] = *reinterpret_cast<const short8v*>(&Ah[r][l16 * 8]);
      al[i] = *reinterpret_cast<const short8v*>(&Al[r][l16 * 8]);
    }
#pragma unroll
    for (int n = 0; n < 2; ++n) {
      const int c = wn * 32 + n * 16 + l15;
      bh[n] = *reinterpret_cast<const short8v*>(&Bh[c][l16 * 8]);
      bl[n] = *reinterpret_cast<const short8v*>(&Bl[c][l16 * 8]);
    }
#pragma unroll
    for (int i = 0; i < 4; ++i)
#pragma unroll
      for (int n = 0; n < 2; ++n) {
        acc[i][n] = __builtin_amdgcn_mfma_f32_16x16x32_bf16(ah[i], bh[n], acc[i][n], 0, 0, 0);
        acc[i][n] = __builtin_amdgcn_mfma_f32_16x16x32_bf16(ah[i], bl[n], acc[i][n], 0, 0, 0);
        acc[i][n] = __builtin_amdgcn_mfma_f32_16x16x32_bf16(al[i], bh[n], acc[i][n], 0, 0, 0);
      }
    __syncthreads();
  }

#pragma unroll
  for (int i = 0; i < 4; ++i) {
#pragma unroll
    for (int n = 0; n < 2; ++n) {
      const int col = col0 + wn * 32 + n * 16 + l15;
      float bs = BIAS ? bias[col] : 0.f;
#pragma unroll
      for (int r = 0; r < 4; ++r) {
        const int row = row0 + wm * 64 + i * 16 + l16 * 4 + r;
        float v = acc[i][n][r] + bs;
        if (RESID) v += resid[(size_t)row * N + col];
        if (RELU)  v = fmaxf(v, 0.f);
        if (PACKOUT) ((uint_t*)Cx)[(size_t)row * N + col] = pack_bf16(v);
        else         ((float*)Cx)[(size_t)row * N + col] = v;
      }
    }
  }
}

// ---------------- MFMA GEMM, bf16x3 split, 64x64 tile (for N=512 GEMMs) ----------------
// 256 threads (4 waves as 2x2), grid (N/64)x(M/64) = 512 blocks for N=512:
// 2 blocks/CU co-resident (20KB LDS each) so one block's MFMA phase hides the
// other's staging + barrier drain (m114-style implicit overlap — the prior
// 128x64 tile ran exactly 1 block/CU with zero cross-block overlap).
template<int N, int K, int AMODE, bool BIAS, bool RESID, bool RELU, bool PACKOUT>
__global__ __launch_bounds__(256) void gemm6464(
    const void* __restrict__ Ax, const float* __restrict__ B,
    const float* __restrict__ bias, const float* __restrict__ resid,
    void* __restrict__ Cx)
{
  __shared__ ushort_t Ah[64][40];
  __shared__ ushort_t Al[64][40];
  __shared__ ushort_t Bh[64][40];   // [col][k]
  __shared__ ushort_t Bl[64][40];

  const int tid = threadIdx.x;
  const int wv = tid >> 6, lane = tid & 63;
  const int wm = wv >> 1;          // 0..1 : 32-row band
  const int wn = wv & 1;           // 0..1 : 32-col half
  const int l15 = lane & 15, l16 = lane >> 4;
  const int row0 = blockIdx.y * 64, col0 = blockIdx.x * 64;

  const int sar = tid >> 2, sak = (tid & 3) * 8;    // A: 64r x 32k, 8/thread
  const int sbc = tid & 63,  sbk = (tid >> 6) * 8;  // B: 64c x 32k, 8/thread

  float4v acc[2][2];
#pragma unroll
  for (int i = 0; i < 2; ++i)
#pragma unroll
    for (int n = 0; n < 2; ++n) acc[i][n] = (float4v)(0.f);

  for (int k0 = 0; k0 < K; k0 += 32) {
    {
      short8v vh, vl;
      if (AMODE == 0) {
        const float* ap = (const float*)Ax + (size_t)(row0 + sar) * K + k0 + sak;
        float4 a0 = *reinterpret_cast<const float4*>(ap);
        float4 a1 = *reinterpret_cast<const float4*>(ap + 4);
        float av[8] = {a0.x, a0.y, a0.z, a0.w, a1.x, a1.y, a1.z, a1.w};
#pragma unroll
        for (int j = 0; j < 8; ++j) {
          ushort_t h, l; split_bf16(av[j], h, l);
          vh[j] = (short)h; vl[j] = (short)l;
        }
      } else {
        const uint_t* ap = (const uint_t*)Ax + (size_t)(row0 + sar) * K + k0 + sak;
        uint4 a0 = *reinterpret_cast<const uint4*>(ap);
        uint4 a1 = *reinterpret_cast<const uint4*>(ap + 4);
        uint_t av[8] = {a0.x, a0.y, a0.z, a0.w, a1.x, a1.y, a1.z, a1.w};
#pragma unroll
        for (int j = 0; j < 8; ++j) {
          vh[j] = (short)(av[j] >> 16);
          vl[j] = (short)(av[j] & 0xffffu);
        }
      }
      *reinterpret_cast<short8v*>(&Ah[sar][sak]) = vh;
      *reinterpret_cast<short8v*>(&Al[sar][sak]) = vl;
    }
    {
      float bv[8];
#pragma unroll
      for (int j = 0; j < 8; ++j)
        bv[j] = B[(size_t)(k0 + sbk + j) * N + col0 + sbc];
      short8v vh, vl;
#pragma unroll
      for (int j = 0; j < 8; ++j) {
        ushort_t h, l; split_bf16(bv[j], h, l);
        vh[j] = (short)h; vl[j] = (short)l;
      }
      *reinterpret_cast<short8v*>(&Bh[sbc][sbk]) = vh;
      *reinterpret_cast<short8v*>(&Bl[sbc][sbk]) = vl;
    }
    __syncthreads();

    short8v ah[2], al[2], bh[2], bl[2];
#pragma unroll
    for (int i = 0; i < 2; ++i) {
      const int r = wm * 32 + i * 16 + l15;
      ah[i] = *reinterpret_cast<const short8v*>(&Ah[r][l16 * 8]);
      al[i] = *reinterpret_cast<const short8v*>(&Al[r][l16 * 8]);
    }
#pragma unroll
    for (int n = 0; n < 2; ++n) {
      const int c = wn * 32 + n * 16 + l15;
      bh[n] = *reinterpret_cast<const short8v*>(&Bh[c][l16 * 8]);
      bl[n] = *reinterpret_cast<const short8v*>(&Bl[c][l16 * 8]);
    }
#pragma unroll
    for (int i = 0; i < 2; ++i)
#pragma unroll
      for (int n = 0; n < 2; ++n) {
        acc[i][n] = __builtin_amdgcn_mfma_f32_16x16x32_bf16(ah[i], bh[n], acc[i][n], 0, 0, 0);
        acc[i][n] = __builtin_amdgcn_mfma_f32_16x16x32_bf16(ah[i], bl[n], acc[i][n], 0, 0, 0);
        acc[i][n] = __builtin_amdgcn_mfma_f32_16x16x32_bf16(al[i], bh[n], acc[i][n], 0, 0, 0);
      }
    __syncthreads();
  }

#pragma unroll
  for (int i = 0; i < 2; ++i) {
#pragma unroll
    for (int n = 0; n < 2; ++n) {
      const int col = col0 + wn * 32 + n * 16 + l15;
      float bs = BIAS ? bias[col] : 0.f;
#pragma unroll
      for (int r = 0; r < 4; ++r) {
        const int row = row0 + wm * 32 + i * 16 + l16 * 4 + r;
        float v = acc[i][n][r] + bs;
        if (RESID) v += resid[(size_t)row * N + col];
        if (RELU)  v = fmaxf(v, 0.f);
        if (PACKOUT) ((uint_t*)Cx)[(size_t)row * N + col] = pack_bf16(v);
        else         ((float*)Cx)[(size_t)row * N + col] = v;
      }
    }
  }
}

// ---------------- layernorm over HID=512, packed bf16-pair output ----------------
__global__ __launch_bounds__(64) void layernorm_k(
    const float* __restrict__ in, const float* __restrict__ g,
    const float* __restrict__ b, uint_t* __restrict__ out)
{
  const int row = blockIdx.x, lane = threadIdx.x;
  const float* p = in + (size_t)row * HID + lane * 8;
  float4 v0 = *reinterpret_cast<const float4*>(p);
  float4 v1 = *reinterpret_cast<const float4*>(p + 4);
  float s = v0.x + v0.y + v0.z + v0.w + v1.x + v1.y + v1.z + v1.w;
  s = rsum64(s);
  const float mean = s * (1.0f / HID);
  float x[8] = {v0.x, v0.y, v0.z, v0.w, v1.x, v1.y, v1.z, v1.w};
  float sq = 0.f;
#pragma unroll
  for (int j = 0; j < 8; ++j) { float d = x[j] - mean; sq += d * d; }
  sq = rsum64(sq);
  const float rstd = rsqrtf(sq * (1.0f / HID) + 1e-5f);
  float4 g0 = *reinterpret_cast<const float4*>(&g[lane * 8]);
  float4 g1 = *reinterpret_cast<const float4*>(&g[lane * 8 + 4]);
  float4 b0 = *reinterpret_cast<const float4*>(&b[lane * 8]);
  float4 b1 = *reinterpret_cast<const float4*>(&b[lane * 8 + 4]);
  float gg[8] = {g0.x, g0.y, g0.z, g0.w, g1.x, g1.y, g1.z, g1.w};
  float bb[8] = {b0.x, b0.y, b0.z, b0.w, b1.x, b1.y, b1.z, b1.w};
  uint_t o[8];
#pragma unroll
  for (int j = 0; j < 8; ++j) o[j] = pack_bf16((x[j] - mean) * rstd * gg[j] + bb[j]);
  uint4 o0 = make_uint4(o[0], o[1], o[2], o[3]);
  uint4 o1 = make_uint4(o[4], o[5], o[6], o[7]);
  uint_t* q = out + (size_t)row * HID + lane * 8;
  *reinterpret_cast<uint4*>(q) = o0;
  *reinterpret_cast<uint4*>(q + 4) = o1;
}

// ---------------- fast-weight recurrence: 4 waves per (b,h) chain, 1 barrier/step ----------------
// Session-best srec (R9/R14, ~313us/dispatch). See R14 header comment for the
// established floor ledger.
__global__ __launch_bounds__(256) void srec4m(
    const float* __restrict__ h,
    const float* __restrict__ Wy0, const float* __restrict__ Wq0,
    const float* __restrict__ Wk0, const float* __restrict__ wb0,
    uint_t* __restrict__ ys)
{
  const int bh = blockIdx.x;
  const int bb = bh >> 3, hh = bh & 7;
  const int tid = threadIdx.x;
  const int wv = tid >> 6, lane = tid & 63;

  __shared__ float xs[2][64];
  __shared__ float q_s[2][64];
  __shared__ float k_s[2][64];
  __shared__ float4 betas4[2];

  float W[64];
  float wbr[4] = {0.f, 0.f, 0.f, 0.f};
  float xrA = 0.f, xrB = 0.f;   // raw-x prefetch registers (alternating)
  float xnreg = 0.f;            // softmax(x(t+1)), carried interval -> interval

  const float* xp = h + (size_t)bb * HID + hh * 64 + lane;
  uint_t* yp = ys + (size_t)bb * HID + hh * 64 + lane;

  if (wv < 3) {
    const float* base = (wv == 0 ? Wy0 : (wv == 1 ? Wq0 : Wk0)) + (size_t)(hh * 64 + lane) * 64;
#pragma unroll
    for (int j = 0; j < 16; ++j) {
      float4 a = reinterpret_cast<const float4*>(base)[j];
      W[4*j] = a.x; W[4*j+1] = a.y; W[4*j+2] = a.z; W[4*j+3] = a.w;
    }
  } else {
    float4 w = *reinterpret_cast<const float4*>(&wb0[(size_t)(hh * 64 + lane) * 4]);
    wbr[0] = w.x; wbr[1] = w.y; wbr[2] = w.z; wbr[3] = w.w;
    float xr0 = xp[0];
    xrA = xp[(size_t)BSZ * HID];       // raw x(1)
    // softmax(x(0)) -> xs[0]   (no max-sub: shift-invariant)
    float e = __expf(xr0);
    float sm = rsum64(e);
    float x0 = e * __builtin_amdgcn_rcpf(sm);
    xs[0][lane] = x0;
    // betas for step 0
    float s0 = rsum64(wbr[0] * x0);
    float s1 = rsum64(wbr[1] * x0);
    float s2 = rsum64(wbr[2] * x0);
    float s3 = rsum64(wbr[3] * x0);
    if (lane == 0)
      betas4[0] = make_float4(__builtin_amdgcn_rcpf(1.f + __expf(-s0)),
                              __builtin_amdgcn_rcpf(1.f + __expf(-s1)),
                              __builtin_amdgcn_rcpf(1.f + __expf(-s2)),
                              __builtin_amdgcn_rcpf(1.f + __expf(-s3)));
  }
  SYNC_LDS();

  // ---- A-part of step T (phase parity P = T&1): matvec + softmax publish ----
  auto Apart = [&](int P, float& XCUR, float& XNEXT, int T) {
    if (wv == 3) {
      if (T + 2 < SLEN) XNEXT = xp[(size_t)(T + 2) * BSZ * HID];  // issue; used 2 intervals later
      // softmax of raw x(T+1) -> xs[1-P]   (no max-sub)
      float e = __expf(XCUR);
      float sm = rsum64(e);
      float xn_ = e * __builtin_amdgcn_rcpf(sm);
      xs[1 - P][lane] = xn_;
      xnreg = xn_;
    } else {
      const float4* xv = reinterpret_cast<const float4*>(xs[P]);
      float a0=0.f,a1=0.f,a2=0.f,a3=0.f,a4=0.f,a5=0.f,a6=0.f,a7=0.f;
#pragma unroll
      for (int j = 0; j < 8; ++j) {
        float4 x1 = xv[2*j], x2 = xv[2*j+1];
        a0 = fmaf(W[8*j+0], x1.x, a0);
        a1 = fmaf(W[8*j+1], x1.y, a1);
        a2 = fmaf(W[8*j+2], x1.z, a2);
        a3 = fmaf(W[8*j+3], x1.w, a3);
        a4 = fmaf(W[8*j+4], x2.x, a4);
        a5 = fmaf(W[8*j+5], x2.y, a5);
        a6 = fmaf(W[8*j+6], x2.z, a6);
        a7 = fmaf(W[8*j+7], x2.w, a7);
      }
      float acc = ((a0 + a1) + (a2 + a3)) + ((a4 + a5) + (a6 + a7));
      if (wv == 0) {
        yp[(size_t)T * BSZ * HID] = pack_bf16(acc);   // fire-and-forget packed store
      } else {
        float e = __expf(acc);             // no max-sub
        float sm = rsum64(e);
        float v = e * __builtin_amdgcn_rcpf(sm);
        float* dst = (wv == 1) ? q_s[P] : k_s[P];
        dst[lane] = v;
      }
    }
  };

  // ---- B-part of step T (P = T&1): W/wb update + betas for step T+1 ----
  auto Bpart = [&](int P) {
    float4 bb4 = betas4[P];
    if (wv < 3) {
      const float4* qv = reinterpret_cast<const float4*>(q_s[P]);
      const float4* kv = reinterpret_cast<const float4*>(k_s[P]);
      float4 karr[16];
      float a0=0.f,a1=0.f,a2=0.f,a3=0.f,a4=0.f,a5=0.f,a6=0.f,a7=0.f;
#pragma unroll
      for (int j = 0; j < 8; ++j) {
        float4 q1 = qv[2*j], k1 = kv[2*j];
        float4 q2 = qv[2*j+1], k2 = kv[2*j+1];
        karr[2*j] = k1; karr[2*j+1] = k2;
        a0 = fmaf(W[8*j+0], q1.x - k1.x, a0);
        a1 = fmaf(W[8*j+1], q1.y - k1.y, a1);
        a2 = fmaf(W[8*j+2], q1.z - k1.z, a2);
        a3 = fmaf(W[8*j+3], q1.w - k1.w, a3);
        a4 = fmaf(W[8*j+4], q2.x - k2.x, a4);
        a5 = fmaf(W[8*j+5], q2.y - k2.y, a5);
        a6 = fmaf(W[8*j+6], q2.z - k2.z, a6);
        a7 = fmaf(W[8*j+7], q2.w - k2.w, a7);
      }
      float dd = ((a0 + a1) + (a2 + a3)) + ((a4 + a5) + (a6 + a7));
      float beta = (wv == 0) ? bb4.x : (wv == 1 ? bb4.y : bb4.z);
      float c = beta * dd;
#pragma unroll
      for (int j = 0; j < 16; ++j) {
        float4 k4 = karr[j];
        W[4*j]   = fmaf(c, k4.x, W[4*j]);
        W[4*j+1] = fmaf(c, k4.y, W[4*j+1]);
        W[4*j+2] = fmaf(c, k4.z, W[4*j+2]);
        W[4*j+3] = fmaf(c, k4.w, W[4*j+3]);
      }
    } else {
      // wb update + next-step betas via 9 INDEPENDENT reductions:
      // s_i(next) = (wbr_i + bk*d_i) . xn = rsum(wbr_i*xn) + d_i * rsum(bk*xn)
      float ql = q_s[P][lane], kl = k_s[P][lane];
      float dl = ql - kl;
      float bk = bb4.w * kl;
      float u0 = rsum64(wbr[0] * xnreg);
      float u1 = rsum64(wbr[1] * xnreg);
      float u2 = rsum64(wbr[2] * xnreg);
      float u3 = rsum64(wbr[3] * xnreg);
      float d0 = rsum64(wbr[0] * dl);
      float d1 = rsum64(wbr[1] * dl);
      float d2 = rsum64(wbr[2] * dl);
      float d3 = rsum64(wbr[3] * dl);
      float g  = rsum64(bk * xnreg);
      wbr[0] = fmaf(bk, d0, wbr[0]);
      wbr[1] = fmaf(bk, d1, wbr[1]);
      wbr[2] = fmaf(bk, d2, wbr[2]);
      wbr[3] = fmaf(bk, d3, wbr[3]);
      float s0 = fmaf(d0, g, u0);
      float s1 = fmaf(d1, g, u1);
      float s2 = fmaf(d2, g, u2);
      float s3 = fmaf(d3, g, u3);
      if (lane == 0)
        betas4[1 - P] = make_float4(__builtin_amdgcn_rcpf(1.f + __expf(-s0)),
                                    __builtin_amdgcn_rcpf(1.f + __expf(-s1)),
                                    __builtin_amdgcn_rcpf(1.f + __expf(-s2)),
                                    __builtin_amdgcn_rcpf(1.f + __expf(-s3)));
    }
  };

  // interval 0: A(0) only
  Apart(0, xrA, xrB, 0);
  SYNC_LDS();
  // intervals 1..254 (pairs): [B(t-1); A(t)] + one barrier each
  for (int t = 1; t < SLEN - 1; t += 2) {
    Bpart(0);  Apart(1, xrB, xrA, t);      SYNC_LDS();
    Bpart(1);  Apart(0, xrA, xrB, t + 1);  SYNC_LDS();
  }
  // final interval: B(254); A(255). Dead update B(255) skipped.
  Bpart(0);  Apart(1, xrB, xrA, SLEN - 1);
}

extern "C" void kernel_launch(void* const* d_in, const int* in_sizes, int n_in,
                              void* d_out, int out_size, void* d_ws, size_t ws_size,
                              hipStream_t stream)
{
  const float* x     = (const float*)d_in[0];
  const float* in_w  = (const float*)d_in[1];
  const float* in_b  = (const float*)d_in[2];
  const float* Wy    = (const float*)d_in[3];
  const float* Wq    = (const float*)d_in[4];
  const float* Wk    = (const float*)d_in[5];
  const float* wb    = (const float*)d_in[6];
  const float* Wout  = (const float*)d_in[7];
  const float* ln_g  = (const float*)d_in[8];
  const float* ln_b  = (const float*)d_in[9];
  const float* ff_w1 = (const float*)d_in[10];
  const float* ff_b1 = (const float*)d_in[11];
  const float* ff_w2 = (const float*)d_in[12];
  const float* ff_b2 = (const float*)d_in[13];
  float* out = (float*)d_out;

  char* ws = (char*)d_ws;
  uint_t* ys   = (uint_t*)ws;                  // 8MB  packed bf16-pair
  uint_t* ffb  = (uint_t*)(ws + (8u  << 20));  // 32MB packed
  uint_t* ybuf = (uint_t*)(ws + (40u << 20));  // 8MB  packed

  // ---- in-projection: 64x64 tiles -> 512 blocks (2/CU). ----
  gemm6464<HID, 512, 0, true, false, false, false><<<dim3(HID/64, MROWS/64), 256, 0, stream>>>(
      x, in_w, in_b, nullptr, out);

  for (int l = 0; l < 2; ++l) {
    srec4m<<<128, 256, 0, stream>>>(out,
                                    Wy + (size_t)l * NH * HD * HD,
                                    Wq + (size_t)l * NH * HD * HD,
                                    Wk + (size_t)l * NH * HD * HD,
                                    wb + (size_t)l * NH * HD * 4,
                                    ys);
    // Wout: A packed ys, resid fp32 out. 64x64 tiles -> 512 blocks (2/CU).
    gemm6464<HID, HID, 1, false, true, false, false><<<dim3(HID/64, MROWS/64), 256, 0, stream>>>(
        ys, Wout + (size_t)l * HID * HID, nullptr, out, out);
    layernorm_k<<<MROWS, 64, 0, stream>>>(out, ln_g + (size_t)l * HID, ln_b + (size_t)l * HID, ybuf);
    // FF1: A packed ybuf, relu, C packed ffb. 128-wide tiles, 512 blocks (2/CU).
    gemm128<FFD, HID, 1, true, false, true, true><<<dim3(FFD/128, MROWS/128), 512, 0, stream>>>(
        ybuf, ff_w1 + (size_t)l * HID * FFD, ff_b1 + (size_t)l * FFD, nullptr, ffb);
    // FF2: A packed ffb, resid fp32 out. 64x64 tiles -> 512 blocks (2/CU).
    gemm6464<HID, FFD, 1, true, true, false, false><<<dim3(HID/64, MROWS/64), 256, 0, stream>>>(
        ffb, ff_w2 + (size_t)l * FFD * HID, ff_b2 + (size_t)l * HID, out, out);
  }
}